// Round 1
// baseline (105.457 us; speedup 1.0000x reference)
//
#include <hip/hip_runtime.h>
#include <hip/hip_bf16.h>

// GTAT integrated: B=8,N=4096,D=256,TD=64,GD=73,L=2 -> 32768 rows, row-parallel.
// Pipeline: TA (t,Tp,p,q) -> TB (beta,T_out,M=T_out@Wo swz, r',u,c, W swizzles)
//  -> big<0> h0=x@Win+bin (+s0)  -> big<1> l=0 -> big<1> l=1 -> big<2> out=LN(h@Wout+bout)

typedef float f32x4 __attribute__((ext_vector_type(4)));
typedef short bf16x8 __attribute__((ext_vector_type(8)));

__device__ __forceinline__ unsigned short f2bf(float f) {
  unsigned int u = __builtin_bit_cast(unsigned int, f);
  u += 0x7FFFu + ((u >> 16) & 1u);   // round-to-nearest-even
  return (unsigned short)(u >> 16);
}
__device__ __forceinline__ float lrelu(float x) { return x > 0.f ? x : 0.01f * x; }

// ---- block reduce helpers (256 threads, all must call) ----
__device__ __forceinline__ float block_sum(float v, float* s4, int t) {
#pragma unroll
  for (int m = 1; m < 64; m <<= 1) v += __shfl_xor(v, m, 64);
  __syncthreads();
  if ((t & 63) == 0) s4[t >> 6] = v;
  __syncthreads();
  return s4[0] + s4[1] + s4[2] + s4[3];
}
__device__ __forceinline__ float block_max(float v, float* s4, int t) {
#pragma unroll
  for (int m = 1; m < 64; m <<= 1) v = fmaxf(v, __shfl_xor(v, m, 64));
  __syncthreads();
  if ((t & 63) == 0) s4[t >> 6] = v;
  __syncthreads();
  return fmaxf(fmaxf(s4[0], s4[1]), fmaxf(s4[2], s4[3]));
}

// B-operand swizzled layout: elem(k,n) -> ((((k>>5)*16 + (n>>4))*4 + ((k>>3)&3))*16 + (n&15))*8 + (k&7)
// lane l reads 16B at byte ((kb*16+ct)*64 + l)*16  => B[kb*32+8*(l>>4)+j][ct*16+(l&15)]
__device__ __forceinline__ int swz_off(int k, int n) {
  return ((((k >> 5) * 16 + (n >> 4)) * 4 + ((k >> 3) & 3)) * 16 + (n & 15)) * 8 + (k & 7);
}
// A-frag LDS byte offset for (k=n, row m in [0,64)), XOR-swizzled to kill bank conflicts
__device__ __forceinline__ int alds_byte(int n, int m) {
  int grp = n >> 3;                                  // kb*4+g, 0..31
  int base = (grp * 64 + m) * 16 + (n & 7) * 2;
  return base ^ ((grp & 7) << 4);
}

// ============ TA: t rows -> Tp rows + p,q  (grid 512 = L*256, 256 thr) ============
__global__ void ta_kernel(const float* __restrict__ gdv,
                          const float* __restrict__ g1W, const float* __restrict__ g1b,
                          const float* __restrict__ g2W, const float* __restrict__ g2b,
                          const float* __restrict__ grW, const float* __restrict__ grb,
                          const float* __restrict__ Wt, const float* __restrict__ bt,
                          const float* __restrict__ wat,
                          float* __restrict__ Tp, float* __restrict__ pb, float* __restrict__ qb) {
  int l = blockIdx.x >> 8, i = blockIdx.x & 255, t = threadIdx.x;
  __shared__ float gs[73], as_[64], ts[64], s4[4];
  float gv = (t < 73) ? gdv[i * 73 + t] : 0.f;
  float gsum = block_sum(gv, s4, t);
  if (t < 73) gs[t] = gv / (gsum + 1e-6f);
  __syncthreads();
  if (t < 64) {
    float a = g1b[t], gr = grb[t];
    for (int k = 0; k < 73; ++k) { float gk = gs[k]; a = fmaf(gk, g1W[k * 64 + t], a); gr = fmaf(gk, grW[k * 64 + t], gr); }
    as_[t] = fmaxf(a, 0.f);
    ts[t] = gr + g2b[t];
  }
  __syncthreads();
  float tv = 0.f;
  if (t < 64) {
    tv = ts[t];
    for (int k = 0; k < 64; ++k) tv = fmaf(as_[k], g2W[k * 64 + t], tv);
  }
  __syncthreads();
  if (t < 64) ts[t] = tv;
  __syncthreads();
  float tp = bt[l * 256 + t];
  for (int k = 0; k < 64; ++k) tp = fmaf(ts[k], Wt[(l * 64 + k) * 256 + t], tp);
  Tp[(l * 256 + i) * 256 + t] = tp;
  float pp = block_sum(tp * wat[l * 512 + t], s4, t);
  float qq = block_sum(tp * wat[l * 512 + 256 + t], s4, t);
  if (t == 0) { pb[l * 256 + i] = pp; qb[l * 256 + i] = qq; }
}

// ====== TB: beta,T_out row -> M row (swz bf16), r', u, c ; + W_in/W_out swizzles ======
__global__ void tb_kernel(const int* __restrict__ adj, const float* __restrict__ Tp,
                          const float* __restrict__ pb, const float* __restrict__ qb,
                          const float* __restrict__ batopo, const float* __restrict__ Wo,
                          const float* __restrict__ wafeat, const float* __restrict__ bafeat,
                          const float* __restrict__ Wf, const float* __restrict__ bfv,
                          const float* __restrict__ Win, const float* __restrict__ Wout,
                          float* __restrict__ rp, float* __restrict__ ub, float* __restrict__ cb,
                          unsigned short* __restrict__ Uws) {
  int b = blockIdx.x, t = threadIdx.x;
  if (b >= 512) {                               // weight swizzle blocks
    int bb = b - 512;
    const float* src = (bb < 16) ? Win : Wout;
    unsigned short* dst = Uws + ((bb < 16) ? 0 : 65536);
    int r0 = (bb & 15) * 16;
    for (int kk = 0; kk < 16; ++kk) {
      int k = r0 + kk;
      dst[swz_off(k, t)] = f2bf(src[k * 256 + t]);
    }
    return;
  }
  int l = b >> 8, i = b & 255;
  __shared__ float beta[256], tout[256], s4[4];
  float e = pb[l * 256 + i] + qb[l * 256 + t] + batopo[l];
  e = lrelu(e);
  if (adj[i * 256 + t] == 0) e = -1e9f;          // where(mask, NEG, lrelu(...))
  float mx = block_max(e, s4, t);
  float w = __expf(e - mx);
  float Z = block_sum(w, s4, t);
  beta[t] = w / Z;
  __syncthreads();
  float acc = 0.f;
  for (int j = 0; j < 256; ++j) acc = fmaf(beta[j], Tp[(l * 256 + j) * 256 + t], acc);
  tout[t] = acc;
  __syncthreads();
  const float* WoL = Wo + l * 65536;
  float macc = 0.f;
  for (int h2 = 0; h2 < 256; ++h2) macc = fmaf(tout[h2], WoL[h2 * 256 + t], macc);
  Uws[131072 + l * 65536 + swz_off(i, t)] = f2bf(macc);   // M_l row i
  const float* wf = wafeat + l * 512;            // wh = wf[0..256), wt = wf[256..512)
  float rsum = block_sum(tout[t] * wf[256 + t], s4, t);
  if (t == 0) rp[l * 256 + i] = rsum + bafeat[l];          // r' = T_out@wt + ba_feat
  float usum = block_sum(Wf[(l * 256 + i) * 256 + t] * wf[t], s4, t);
  if (t == 0) ub[l * 256 + i] = usum;                      // u = Wf@wh
  if (i == 0) {
    float csum = block_sum(bfv[l * 256 + t] * wf[t], s4, t);
    if (t == 0) cb[l] = csum;                              // c = bf.wh
  }
}

// ============ big kernel: one MFMA GEMM stage, 512 WGs x 256 thr, 64 rows/WG ============
// MODE 0: h0 = x@Win + bin ; store frag-f32 h, s0 = h0.u0 + c0
// MODE 1: alpha = softmax_f(lrelu(s + r'_f)); h = LN(alpha@M + bo + h); (l==0: s1)
// MODE 2: out = LN(h@Wout + bout)
template <int MODE>
__global__ __launch_bounds__(256, 2) void big_kernel(
    const float* __restrict__ x, float* __restrict__ hfrag, float* __restrict__ sbuf,
    const float* __restrict__ rp, const float* __restrict__ ub, const float* __restrict__ cb,
    const unsigned short* __restrict__ Uws,
    const float* __restrict__ bin, const float* __restrict__ bo,
    const float* __restrict__ lng, const float* __restrict__ lnb,
    const float* __restrict__ bout, const float* __restrict__ lngf, const float* __restrict__ lnbf,
    float* __restrict__ out, int l) {
  __shared__ unsigned short alds[16384];          // 32KB A fragments (bf16)
  __shared__ float v0[256], v1[256], v2[256], v3[256];
  __shared__ float r_s[256];
  __shared__ float red[4][64][2];
  __shared__ float mr_s[64][2];
  __shared__ float row_s[64], invz_s[64], mx_s[64];
  __shared__ float scal_s[4];
  char* smc = (char*)alds;

  int wg = blockIdx.x, t = threadIdx.x;
  int wid = t >> 6, lane = t & 63;
  int li = lane & 15, g = lane >> 4;
  int rowbase = wg * 64;
  float* hf = hfrag + wg * 16384;

  // ---- prologue: stage A into LDS frag layout ----
  if (MODE == 0) {
    v0[t] = bin[t]; v1[t] = ub[t];
#pragma unroll
    for (int it = 0; it < 16; ++it) {
      int flat = it * 1024 + t * 4;
      int m = flat >> 8, col = flat & 255;
      const float4 xv = *(const float4*)(x + (rowbase + m) * 256 + col);
      ushort4 pk; pk.x = f2bf(xv.x); pk.y = f2bf(xv.y); pk.z = f2bf(xv.z); pk.w = f2bf(xv.w);
      *(ushort4*)(smc + alds_byte(col, m)) = pk;
    }
  } else if (MODE == 2) {
    v0[t] = bout[t]; v2[t] = lngf[t]; v3[t] = lnbf[t];
#pragma unroll
    for (int it = 0; it < 16; ++it) {
      int flat = it * 1024 + t * 4;
      const float4 hv = *(const float4*)(hf + flat);
      int lp = flat & 63, reg = (flat >> 6) & 3, ct = (flat >> 8) & 3, rt = (flat >> 10) & 3, wp = flat >> 12;
      int m = rt * 16 + (lp >> 4) * 4 + reg;
      int n = wp * 64 + ct * 16 + (lp & 15);
      ushort4 pk; pk.x = f2bf(hv.x); pk.y = f2bf(hv.y); pk.z = f2bf(hv.z); pk.w = f2bf(hv.w);
      *(ushort4*)(smc + alds_byte(n, m)) = pk;
    }
  } else {  // MODE 1: generate alpha
    v0[t] = bo[l * 256 + t]; v2[t] = lng[l * 256 + t]; v3[t] = lnb[l * 256 + t];
    v1[t] = (l == 0) ? ub[256 + t] : 0.f;
    r_s[t] = rp[l * 256 + t];
    if (t < 64) row_s[t] = sbuf[rowbase + t];
    __syncthreads();
    if (wid == 0) {  // R = max_f r'
      float m2 = fmaxf(fmaxf(r_s[lane], r_s[lane + 64]), fmaxf(r_s[lane + 128], r_s[lane + 192]));
#pragma unroll
      for (int mm = 1; mm < 64; mm <<= 1) m2 = fmaxf(m2, __shfl_xor(m2, mm, 64));
      if (lane == 0) scal_s[0] = m2;
    }
    __syncthreads();
    float Rm = scal_s[0];
    {  // Z pass: 4 threads per row
      int row = t >> 2, p4 = t & 3;
      float sm = row_s[row];
      float mx = lrelu(sm + Rm);  // exact max: lrelu monotone
      float z = 0.f;
      for (int f = p4 * 64; f < p4 * 64 + 64; ++f) z += __expf(lrelu(sm + r_s[f]) - mx);
      red[p4][row][0] = z;
      if (p4 == 0) mx_s[row] = mx;
    }
    __syncthreads();
    if (t < 64) {
      float Z = red[0][t][0] + red[1][t][0] + red[2][t][0] + red[3][t][0];
      invz_s[t] = 1.f / Z;
    }
    __syncthreads();
#pragma unroll
    for (int it = 0; it < 16; ++it) {
      int flat = it * 1024 + t * 4;
      int m = flat >> 8, f0 = flat & 255;
      float sm = row_s[m], mx = mx_s[m], iz = invz_s[m];
      ushort4 pk;
      pk.x = f2bf(__expf(lrelu(sm + r_s[f0 + 0]) - mx) * iz);
      pk.y = f2bf(__expf(lrelu(sm + r_s[f0 + 1]) - mx) * iz);
      pk.z = f2bf(__expf(lrelu(sm + r_s[f0 + 2]) - mx) * iz);
      pk.w = f2bf(__expf(lrelu(sm + r_s[f0 + 3]) - mx) * iz);
      *(ushort4*)(smc + alds_byte(f0, m)) = pk;
    }
  }
  __syncthreads();

  // ---- K loop: wave = 64 rows x 64 cols, 16x16x32 bf16 MFMA ----
  const bf16x8* Bw = (const bf16x8*)(Uws + (MODE == 0 ? 0 : (MODE == 2 ? 65536 : 131072 + l * 65536)));
  f32x4 acc[4][4];
#pragma unroll
  for (int a = 0; a < 4; ++a)
#pragma unroll
    for (int bq = 0; bq < 4; ++bq) { f32x4 z = {0.f, 0.f, 0.f, 0.f}; acc[a][bq] = z; }
#pragma unroll
  for (int kb = 0; kb < 8; ++kb) {
    int grp = kb * 4 + g;
    int abase = (((grp * 64 + li) * 16) ^ ((grp & 7) << 4));
    bf16x8 af[4], bfr[4];
#pragma unroll
    for (int rt = 0; rt < 4; ++rt) af[rt] = *(const bf16x8*)(smc + abase + rt * 256);
#pragma unroll
    for (int ct = 0; ct < 4; ++ct) bfr[ct] = Bw[(kb * 16 + wid * 4 + ct) * 64 + lane];
#pragma unroll
    for (int rt = 0; rt < 4; ++rt)
#pragma unroll
      for (int ct = 0; ct < 4; ++ct)
        acc[rt][ct] = __builtin_amdgcn_mfma_f32_16x16x32_bf16(af[rt], bfr[ct], acc[rt][ct], 0, 0, 0);
  }

  // ---- epilogue ----
  int ncol[4]; float bv[4];
#pragma unroll
  for (int ct = 0; ct < 4; ++ct) { ncol[ct] = wid * 64 + ct * 16 + li; bv[ct] = v0[ncol[ct]]; }

  if (MODE == 0) {
    float uv[4];
#pragma unroll
    for (int ct = 0; ct < 4; ++ct) uv[ct] = v1[ncol[ct]];
#pragma unroll
    for (int rt = 0; rt < 4; ++rt) {
      float sp[4] = {0, 0, 0, 0};
#pragma unroll
      for (int ct = 0; ct < 4; ++ct)
#pragma unroll
        for (int r = 0; r < 4; ++r) {
          float v = acc[rt][ct][r] + bv[ct];
          hf[(((wid * 4 + rt) * 4 + ct) * 4 + r) * 64 + lane] = v;
          sp[r] = fmaf(v, uv[ct], sp[r]);
        }
#pragma unroll
      for (int r = 0; r < 4; ++r) {
        float sv = sp[r];
#pragma unroll
        for (int mm = 1; mm < 16; mm <<= 1) sv += __shfl_xor(sv, mm, 64);
        if (li == 0) red[wid][rt * 16 + g * 4 + r][0] = sv;
      }
    }
    __syncthreads();
    if (t < 64) sbuf[rowbase + t] = red[0][t][0] + red[1][t][0] + red[2][t][0] + red[3][t][0] + cb[0];
    return;
  }

  // MODE 1/2 shared LN path
  if (MODE == 1) {
#pragma unroll
    for (int rt = 0; rt < 4; ++rt)
#pragma unroll
      for (int ct = 0; ct < 4; ++ct)
#pragma unroll
        for (int r = 0; r < 4; ++r)
          acc[rt][ct][r] += bv[ct] + hf[(((wid * 4 + rt) * 4 + ct) * 4 + r) * 64 + lane];
  } else {
#pragma unroll
    for (int rt = 0; rt < 4; ++rt)
#pragma unroll
      for (int ct = 0; ct < 4; ++ct)
#pragma unroll
        for (int r = 0; r < 4; ++r) acc[rt][ct][r] += bv[ct];
  }
  // LN stats
#pragma unroll
  for (int rt = 0; rt < 4; ++rt) {
    float s0[4] = {0, 0, 0, 0}, q0[4] = {0, 0, 0, 0};
#pragma unroll
    for (int ct = 0; ct < 4; ++ct)
#pragma unroll
      for (int r = 0; r < 4; ++r) {
        float v = acc[rt][ct][r];
        s0[r] += v; q0[r] = fmaf(v, v, q0[r]);
      }
#pragma unroll
    for (int r = 0; r < 4; ++r) {
      float a = s0[r], bq = q0[r];
#pragma unroll
      for (int mm = 1; mm < 16; mm <<= 1) { a += __shfl_xor(a, mm, 64); bq += __shfl_xor(bq, mm, 64); }
      if (li == 0) { int row = rt * 16 + g * 4 + r; red[wid][row][0] = a; red[wid][row][1] = bq; }
    }
  }
  __syncthreads();
  if (t < 64) {
    float S = red[0][t][0] + red[1][t][0] + red[2][t][0] + red[3][t][0];
    float Q = red[0][t][1] + red[1][t][1] + red[2][t][1] + red[3][t][1];
    float mean = S * (1.f / 256.f);
    float var = Q * (1.f / 256.f) - mean * mean;
    mr_s[t][0] = mean; mr_s[t][1] = rsqrtf(var + 1e-5f);
  }
  __syncthreads();
  float gv4[4], b2[4], uv[4];
#pragma unroll
  for (int ct = 0; ct < 4; ++ct) {
    gv4[ct] = v2[ncol[ct]]; b2[ct] = v3[ncol[ct]];
    uv[ct] = (MODE == 1) ? v1[ncol[ct]] : 0.f;
  }
  bool do_s = (MODE == 1) && (l == 0);
#pragma unroll
  for (int rt = 0; rt < 4; ++rt) {
    float sp[4] = {0, 0, 0, 0};
#pragma unroll
    for (int r = 0; r < 4; ++r) {
      int row = rt * 16 + g * 4 + r;
      float mean = mr_s[row][0], rstd = mr_s[row][1];
#pragma unroll
      for (int ct = 0; ct < 4; ++ct) {
        float v = (acc[rt][ct][r] - mean) * rstd * gv4[ct] + b2[ct];
        if (MODE == 1) {
          hf[(((wid * 4 + rt) * 4 + ct) * 4 + r) * 64 + lane] = v;
          sp[r] = fmaf(v, uv[ct], sp[r]);
        } else {
          out[(rowbase + row) * 256 + ncol[ct]] = v;
        }
      }
    }
    if (do_s) {
#pragma unroll
      for (int r = 0; r < 4; ++r) {
        float sv = sp[r];
#pragma unroll
        for (int mm = 1; mm < 16; mm <<= 1) sv += __shfl_xor(sv, mm, 64);
        if (li == 0) red[wid][rt * 16 + g * 4 + r][0] = sv;
      }
    }
  }
  if (do_s) {
    __syncthreads();
    if (t < 64) sbuf[rowbase + t] = red[0][t][0] + red[1][t][0] + red[2][t][0] + red[3][t][0] + cb[1];
  }
}

extern "C" void kernel_launch(void* const* d_in, const int* in_sizes, int n_in,
                              void* d_out, int out_size, void* d_ws, size_t ws_size,
                              hipStream_t stream) {
  const float* x    = (const float*)d_in[0];
  const int*   adj  = (const int*)d_in[1];
  const float* gdv  = (const float*)d_in[2];
  const float* Win  = (const float*)d_in[3];
  const float* bin  = (const float*)d_in[4];
  const float* Wout = (const float*)d_in[5];
  const float* bout = (const float*)d_in[6];
  const float* g1W  = (const float*)d_in[7];
  const float* g1b  = (const float*)d_in[8];
  const float* g2W  = (const float*)d_in[9];
  const float* g2b  = (const float*)d_in[10];
  const float* grW  = (const float*)d_in[11];
  const float* grb  = (const float*)d_in[12];
  const float* lngf = (const float*)d_in[13];
  const float* lnbf = (const float*)d_in[14];
  const float* Wf   = (const float*)d_in[15];
  const float* bfv  = (const float*)d_in[16];
  const float* Wt   = (const float*)d_in[17];
  const float* bt   = (const float*)d_in[18];
  const float* waf  = (const float*)d_in[19];
  const float* baf  = (const float*)d_in[20];
  const float* wat  = (const float*)d_in[21];
  const float* bat  = (const float*)d_in[22];
  const float* Wo   = (const float*)d_in[23];
  const float* bo   = (const float*)d_in[24];
  const float* lng  = (const float*)d_in[25];
  const float* lnb  = (const float*)d_in[26];
  float* out = (float*)d_out;

  float* W = (float*)d_ws;                 // ws usage ~33.2 MB total
  float* hfrag = W;                        // 32768*256 f32 frag-layout h
  float* sbuf  = W + 8388608;              // 32768
  float* Tp    = W + 8421376;              // 2*256*256
  float* pb    = W + 8552448;              // 2*256
  float* qb    = W + 8552960;
  float* rp    = W + 8553472;
  float* ub    = W + 8553984;
  float* cb    = W + 8554496;              // 2 (+pad)
  unsigned short* Uws = (unsigned short*)(W + 8554560);  // Win|Wout|M0|M1 swz bf16

  ta_kernel<<<512, 256, 0, stream>>>(gdv, g1W, g1b, g2W, g2b, grW, grb, Wt, bt, wat, Tp, pb, qb);
  tb_kernel<<<544, 256, 0, stream>>>(adj, Tp, pb, qb, bat, Wo, waf, baf, Wf, bfv, Win, Wout, rp, ub, cb, Uws);
  big_kernel<0><<<512, 256, 0, stream>>>(x, hfrag, sbuf, rp, ub, cb, Uws, bin,
                                         nullptr, nullptr, nullptr, nullptr, nullptr, nullptr, nullptr, 0);
  big_kernel<1><<<512, 256, 0, stream>>>(x, hfrag, sbuf, rp, ub, cb, Uws, bin,
                                         bo, lng, lnb, nullptr, nullptr, nullptr, nullptr, 0);
  big_kernel<1><<<512, 256, 0, stream>>>(x, hfrag, sbuf, rp, ub, cb, Uws, bin,
                                         bo, lng, lnb, nullptr, nullptr, nullptr, nullptr, 1);
  big_kernel<2><<<512, 256, 0, stream>>>(x, hfrag, sbuf, rp, ub, cb, Uws, nullptr,
                                         nullptr, nullptr, nullptr, bout, lngf, lnbf, out, 0);
}

// Round 2
// 87.213 us; speedup vs baseline: 1.2092x; 1.2092x over previous
//
#include <hip/hip_runtime.h>
#include <hip/hip_bf16.h>

// GTAT integrated: B=8,N=4096,D=256,TD=64,GD=73,L=2 -> 32768 rows, row-parallel.
// Pipeline: TA (t,Tp,p,q) -> TB (beta,T_out,M=T_out@Wo swz, r',u,c, W swizzles)
//  -> fused (all 4 GEMM stages, h kept in registers, 64 rows/WG x 512 thr)

typedef float f32x4 __attribute__((ext_vector_type(4)));
typedef short bf16x8 __attribute__((ext_vector_type(8)));

__device__ __forceinline__ unsigned short f2bf(float f) {
  unsigned int u = __builtin_bit_cast(unsigned int, f);
  u += 0x7FFFu + ((u >> 16) & 1u);   // round-to-nearest-even
  return (unsigned short)(u >> 16);
}
__device__ __forceinline__ float bf2f(unsigned short u) {
  return __builtin_bit_cast(float, (unsigned int)u << 16);
}
__device__ __forceinline__ float lrelu(float x) { return x > 0.f ? x : 0.01f * x; }

// ---- block reduce helpers (256 threads, all must call) ----
__device__ __forceinline__ float block_sum(float v, float* s4, int t) {
#pragma unroll
  for (int m = 1; m < 64; m <<= 1) v += __shfl_xor(v, m, 64);
  __syncthreads();
  if ((t & 63) == 0) s4[t >> 6] = v;
  __syncthreads();
  return s4[0] + s4[1] + s4[2] + s4[3];
}
__device__ __forceinline__ float block_max(float v, float* s4, int t) {
#pragma unroll
  for (int m = 1; m < 64; m <<= 1) v = fmaxf(v, __shfl_xor(v, m, 64));
  __syncthreads();
  if ((t & 63) == 0) s4[t >> 6] = v;
  __syncthreads();
  return fmaxf(fmaxf(s4[0], s4[1]), fmaxf(s4[2], s4[3]));
}

// B-operand swizzled layout: elem(k,n) -> ((((k>>5)*16 + (n>>4))*4 + ((k>>3)&3))*16 + (n&15))*8 + (k&7)
__device__ __forceinline__ int swz_off(int k, int n) {
  return ((((k >> 5) * 16 + (n >> 4)) * 4 + ((k >> 3) & 3)) * 16 + (n & 15)) * 8 + (k & 7);
}
// A-frag LDS byte offset for (k=n, row m in [0,64)), XOR-swizzled
__device__ __forceinline__ int alds_byte(int n, int m) {
  int grp = n >> 3;
  int base = (grp * 64 + m) * 16 + (n & 7) * 2;
  return base ^ ((grp & 7) << 4);
}

// ============ TA: t rows -> Tp rows + p,q  (grid 512 = L*256, 256 thr) ============
__global__ void ta_kernel(const float* __restrict__ gdv,
                          const float* __restrict__ g1W, const float* __restrict__ g1b,
                          const float* __restrict__ g2W, const float* __restrict__ g2b,
                          const float* __restrict__ grW, const float* __restrict__ grb,
                          const float* __restrict__ Wt, const float* __restrict__ bt,
                          const float* __restrict__ wat,
                          float* __restrict__ Tp, float* __restrict__ pb, float* __restrict__ qb) {
  int l = blockIdx.x >> 8, i = blockIdx.x & 255, t = threadIdx.x;
  __shared__ float gs[73], as_[64], ts[64], s4[4];
  float gv = (t < 73) ? gdv[i * 73 + t] : 0.f;
  float gsum = block_sum(gv, s4, t);
  if (t < 73) gs[t] = gv / (gsum + 1e-6f);
  __syncthreads();
  if (t < 64) {
    float a = g1b[t], gr = grb[t];
    for (int k = 0; k < 73; ++k) { float gk = gs[k]; a = fmaf(gk, g1W[k * 64 + t], a); gr = fmaf(gk, grW[k * 64 + t], gr); }
    as_[t] = fmaxf(a, 0.f);
    ts[t] = gr + g2b[t];
  }
  __syncthreads();
  float tv = 0.f;
  if (t < 64) {
    tv = ts[t];
    for (int k = 0; k < 64; ++k) tv = fmaf(as_[k], g2W[k * 64 + t], tv);
  }
  __syncthreads();
  if (t < 64) ts[t] = tv;
  __syncthreads();
  float tp = bt[l * 256 + t];
  for (int k = 0; k < 64; ++k) tp = fmaf(ts[k], Wt[(l * 64 + k) * 256 + t], tp);
  Tp[(l * 256 + i) * 256 + t] = tp;
  float pp = block_sum(tp * wat[l * 512 + t], s4, t);
  float qq = block_sum(tp * wat[l * 512 + 256 + t], s4, t);
  if (t == 0) { pb[l * 256 + i] = pp; qb[l * 256 + i] = qq; }
}

// ====== TB: beta,T_out row -> M row (swz bf16), r', u, c ; + W_in/W_out swizzles ======
__global__ void tb_kernel(const int* __restrict__ adj, const float* __restrict__ Tp,
                          const float* __restrict__ pb, const float* __restrict__ qb,
                          const float* __restrict__ batopo, const float* __restrict__ Wo,
                          const float* __restrict__ wafeat, const float* __restrict__ bafeat,
                          const float* __restrict__ Wf, const float* __restrict__ bfv,
                          const float* __restrict__ Win, const float* __restrict__ Wout,
                          float* __restrict__ rp, float* __restrict__ ub, float* __restrict__ cb,
                          unsigned short* __restrict__ Uws) {
  int b = blockIdx.x, t = threadIdx.x;
  if (b >= 512) {                               // weight swizzle blocks
    int bb = b - 512;
    const float* src = (bb < 16) ? Win : Wout;
    unsigned short* dst = Uws + ((bb < 16) ? 0 : 65536);
    int r0 = (bb & 15) * 16;
    for (int kk = 0; kk < 16; ++kk) {
      int k = r0 + kk;
      dst[swz_off(k, t)] = f2bf(src[k * 256 + t]);
    }
    return;
  }
  int l = b >> 8, i = b & 255;
  __shared__ float beta[256], tout[256], s4[4];
  float e = pb[l * 256 + i] + qb[l * 256 + t] + batopo[l];
  e = lrelu(e);
  if (adj[i * 256 + t] == 0) e = -1e9f;
  float mx = block_max(e, s4, t);
  float w = __expf(e - mx);
  float Z = block_sum(w, s4, t);
  beta[t] = w / Z;
  __syncthreads();
  float acc = 0.f;
  for (int j = 0; j < 256; ++j) acc = fmaf(beta[j], Tp[(l * 256 + j) * 256 + t], acc);
  tout[t] = acc;
  __syncthreads();
  const float* WoL = Wo + l * 65536;
  float macc = 0.f;
  for (int h2 = 0; h2 < 256; ++h2) macc = fmaf(tout[h2], WoL[h2 * 256 + t], macc);
  Uws[131072 + l * 65536 + swz_off(i, t)] = f2bf(macc);   // M_l row i
  const float* wf = wafeat + l * 512;
  float rsum = block_sum(tout[t] * wf[256 + t], s4, t);
  if (t == 0) rp[l * 256 + i] = rsum + bafeat[l];
  float usum = block_sum(Wf[(l * 256 + i) * 256 + t] * wf[t], s4, t);
  if (t == 0) ub[l * 256 + i] = usum;
  if (i == 0) {
    float csum = block_sum(bfv[l * 256 + t] * wf[t], s4, t);
    if (t == 0) cb[l] = csum;
  }
}

// ============ fused kernel: all 4 GEMM stages, 512 WGs x 512 thr, 64 rows/WG ============
// wave tile = 64 rows x 32 cols (4x2 frags of 16x16x32). h kept in regs (32 f32/thread).
__device__ __forceinline__ void kloop(const char* smc, const unsigned short* Bws,
                                      int wid, int lane, int li, int g, f32x4 acc[4][2]) {
  const bf16x8* Bw = (const bf16x8*)Bws;
#pragma unroll
  for (int kb = 0; kb < 8; ++kb) {
    int grp = kb * 4 + g;
    int abase = ((grp * 64 + li) * 16) ^ ((grp & 7) << 4);
    bf16x8 af[4], bfr[2];
#pragma unroll
    for (int rt = 0; rt < 4; ++rt) af[rt] = *(const bf16x8*)(smc + abase + rt * 256);
#pragma unroll
    for (int ct = 0; ct < 2; ++ct) bfr[ct] = Bw[(kb * 16 + wid * 2 + ct) * 64 + lane];
#pragma unroll
    for (int rt = 0; rt < 4; ++rt)
#pragma unroll
      for (int ct = 0; ct < 2; ++ct)
        acc[rt][ct] = __builtin_amdgcn_mfma_f32_16x16x32_bf16(af[rt], bfr[ct], acc[rt][ct], 0, 0, 0);
  }
}

#define S_REDUCE(UBARR, CBV)                                                   \
  {                                                                            \
    _Pragma("unroll") for (int rt = 0; rt < 4; ++rt) {                         \
      float sp[4] = {0.f, 0.f, 0.f, 0.f};                                      \
      _Pragma("unroll") for (int ct = 0; ct < 2; ++ct) {                       \
        float uvv = UBARR[ncol[ct]];                                           \
        _Pragma("unroll") for (int r = 0; r < 4; ++r)                          \
          sp[r] = fmaf(h[rt][ct][r], uvv, sp[r]);                              \
      }                                                                        \
      _Pragma("unroll") for (int r = 0; r < 4; ++r) {                          \
        float sv = sp[r];                                                      \
        sv += __shfl_xor(sv, 1, 64); sv += __shfl_xor(sv, 2, 64);              \
        sv += __shfl_xor(sv, 4, 64); sv += __shfl_xor(sv, 8, 64);              \
        if (li == 0) red[wid][rt * 16 + g * 4 + r][0] = sv;                    \
      }                                                                        \
    }                                                                          \
    __syncthreads();                                                           \
    if (t < 64) {                                                              \
      float S = 0.f;                                                           \
      _Pragma("unroll") for (int w = 0; w < 8; ++w) S += red[w][t][0];         \
      row_s[t] = S + (CBV);                                                    \
    }                                                                          \
    __syncthreads();                                                           \
  }

__global__ __launch_bounds__(512, 4) void fused_kernel(
    const float* __restrict__ x,
    const float* __restrict__ rp, const float* __restrict__ ub, const float* __restrict__ cbp,
    const unsigned short* __restrict__ Uws,
    const float* __restrict__ bin, const float* __restrict__ bo,
    const float* __restrict__ lng, const float* __restrict__ lnb,
    const float* __restrict__ bout, const float* __restrict__ lngf, const float* __restrict__ lnbf,
    float* __restrict__ out) {
  __shared__ unsigned short alds[16384];     // 32KB A fragments
  __shared__ float c_bin[256], c_bout[256], c_lngf[256], c_lnbf[256];
  __shared__ float c_ub[2][256], c_bo[2][256], c_lng[2][256], c_lnb[2][256], c_rp[2][256];
  __shared__ float red[8][64][2];
  __shared__ float row_s[64], invz_s[64];
  __shared__ float mr_s[64][2];
  __shared__ float scal_s[4];                // Rm0, Rm1, cb0, cb1
  char* smc = (char*)alds;

  const int wg = blockIdx.x, t = threadIdx.x;
  const int wid = t >> 6, lane = t & 63, li = lane & 15, g = lane >> 4;
  const int rowbase = wg * 64;
  int ncol[2]; ncol[0] = wid * 32 + li; ncol[1] = wid * 32 + 16 + li;

  // constants -> LDS
  if (t < 256) {
    c_bin[t] = bin[t]; c_ub[0][t] = ub[t]; c_bo[0][t] = bo[t];
    c_lng[0][t] = lng[t]; c_lnb[0][t] = lnb[t]; c_rp[0][t] = rp[t];
  } else {
    int u = t - 256;
    c_bout[u] = bout[u]; c_lngf[u] = lngf[u]; c_lnbf[u] = lnbf[u];
    c_ub[1][u] = ub[256 + u]; c_bo[1][u] = bo[256 + u];
    c_lng[1][u] = lng[256 + u]; c_lnb[1][u] = lnb[256 + u]; c_rp[1][u] = rp[256 + u];
  }
  if (t == 0) { scal_s[2] = cbp[0]; scal_s[3] = cbp[1]; }

  // stage x -> alds (bf16, A-frag layout)
#pragma unroll
  for (int it = 0; it < 8; ++it) {
    int flat = it * 2048 + t * 4;
    int m = flat >> 8, col = flat & 255;
    const float4 xv = *(const float4*)(x + (rowbase + m) * 256 + col);
    ushort4 pk; pk.x = f2bf(xv.x); pk.y = f2bf(xv.y); pk.z = f2bf(xv.z); pk.w = f2bf(xv.w);
    *(ushort4*)(smc + alds_byte(col, m)) = pk;
  }
  __syncthreads();
  if (wid < 2) {   // Rm_l = max_f r'_l
    float m2 = fmaxf(fmaxf(c_rp[wid][lane], c_rp[wid][lane + 64]),
                     fmaxf(c_rp[wid][lane + 128], c_rp[wid][lane + 192]));
#pragma unroll
    for (int mm = 1; mm < 64; mm <<= 1) m2 = fmaxf(m2, __shfl_xor(m2, mm, 64));
    if (lane == 0) scal_s[wid] = m2;
  }

  float h[4][2][4];

  // ---- stage 0: h0 = x@Win + bin ; s0 ----
  {
    f32x4 acc[4][2];
#pragma unroll
    for (int a = 0; a < 4; ++a)
#pragma unroll
      for (int c = 0; c < 2; ++c) { f32x4 z = {0.f, 0.f, 0.f, 0.f}; acc[a][c] = z; }
    kloop(smc, Uws, wid, lane, li, g, acc);
#pragma unroll
    for (int rt = 0; rt < 4; ++rt)
#pragma unroll
      for (int ct = 0; ct < 2; ++ct)
#pragma unroll
        for (int r = 0; r < 4; ++r) h[rt][ct][r] = acc[rt][ct][r] + c_bin[ncol[ct]];
    S_REDUCE(c_ub[0], scal_s[2]);
  }

  // ---- layers ----
#pragma unroll 1
  for (int l = 0; l < 2; ++l) {
    // alpha (un-normalized, bf16) -> alds ; Z per row
    {
      int zrow = t >> 3, p8 = t & 7;
      float sm = row_s[zrow];
      float mx = lrelu(sm + scal_s[l]);   // exact: lrelu monotone
      float z = 0.f;
      for (int f = p8 * 32; f < p8 * 32 + 32; ++f) {
        float w = __expf(lrelu(sm + c_rp[l][f]) - mx);
        unsigned short wb = f2bf(w);
        z += bf2f(wb);
        *(unsigned short*)(smc + alds_byte(f, zrow)) = wb;
      }
      red[p8][zrow][0] = z;
    }
    __syncthreads();
    if (t < 64) {
      float Z = 0.f;
#pragma unroll
      for (int w = 0; w < 8; ++w) Z += red[w][t][0];
      invz_s[t] = 1.f / Z;
    }
    __syncthreads();

    f32x4 acc[4][2];
#pragma unroll
    for (int a = 0; a < 4; ++a)
#pragma unroll
      for (int c = 0; c < 2; ++c) { f32x4 z = {0.f, 0.f, 0.f, 0.f}; acc[a][c] = z; }
    kloop(smc, Uws + 131072 + l * 65536, wid, lane, li, g, acc);

    // h = LN(acc/Z + bo + h)
#pragma unroll
    for (int rt = 0; rt < 4; ++rt)
#pragma unroll
      for (int r = 0; r < 4; ++r) {
        int row = rt * 16 + g * 4 + r;
        float iz = invz_s[row];
#pragma unroll
        for (int ct = 0; ct < 2; ++ct)
          h[rt][ct][r] = fmaf(acc[rt][ct][r], iz, c_bo[l][ncol[ct]] + h[rt][ct][r]);
      }
#pragma unroll
    for (int rt = 0; rt < 4; ++rt) {
      float s0[4] = {0, 0, 0, 0}, q0[4] = {0, 0, 0, 0};
#pragma unroll
      for (int ct = 0; ct < 2; ++ct)
#pragma unroll
        for (int r = 0; r < 4; ++r) { float v = h[rt][ct][r]; s0[r] += v; q0[r] = fmaf(v, v, q0[r]); }
#pragma unroll
      for (int r = 0; r < 4; ++r) {
        float a = s0[r], bq = q0[r];
        a += __shfl_xor(a, 1, 64); bq += __shfl_xor(bq, 1, 64);
        a += __shfl_xor(a, 2, 64); bq += __shfl_xor(bq, 2, 64);
        a += __shfl_xor(a, 4, 64); bq += __shfl_xor(bq, 4, 64);
        a += __shfl_xor(a, 8, 64); bq += __shfl_xor(bq, 8, 64);
        if (li == 0) { int row = rt * 16 + g * 4 + r; red[wid][row][0] = a; red[wid][row][1] = bq; }
      }
    }
    __syncthreads();
    if (t < 64) {
      float S = 0.f, Q = 0.f;
#pragma unroll
      for (int w = 0; w < 8; ++w) { S += red[w][t][0]; Q += red[w][t][1]; }
      float mean = S * (1.f / 256.f);
      float var = Q * (1.f / 256.f) - mean * mean;
      mr_s[t][0] = mean; mr_s[t][1] = rsqrtf(var + 1e-5f);
    }
    __syncthreads();
#pragma unroll
    for (int rt = 0; rt < 4; ++rt)
#pragma unroll
      for (int r = 0; r < 4; ++r) {
        int row = rt * 16 + g * 4 + r;
        float mean = mr_s[row][0], rstd = mr_s[row][1];
#pragma unroll
        for (int ct = 0; ct < 2; ++ct)
          h[rt][ct][r] = (h[rt][ct][r] - mean) * rstd * c_lng[l][ncol[ct]] + c_lnb[l][ncol[ct]];
      }
    if (l == 0) S_REDUCE(c_ub[1], scal_s[3]);
  }

  // ---- stage 3: out = LN(h@Wout + bout) ----
  // h -> alds (A-frag layout, bf16)
#pragma unroll
  for (int rt = 0; rt < 4; ++rt)
#pragma unroll
    for (int ct = 0; ct < 2; ++ct)
#pragma unroll
      for (int r = 0; r < 4; ++r) {
        int row = rt * 16 + g * 4 + r;
        *(unsigned short*)(smc + alds_byte(ncol[ct], row)) = f2bf(h[rt][ct][r]);
      }
  __syncthreads();
  {
    f32x4 acc[4][2];
#pragma unroll
    for (int a = 0; a < 4; ++a)
#pragma unroll
      for (int c = 0; c < 2; ++c) { f32x4 z = {0.f, 0.f, 0.f, 0.f}; acc[a][c] = z; }
    kloop(smc, Uws + 65536, wid, lane, li, g, acc);
#pragma unroll
    for (int rt = 0; rt < 4; ++rt)
#pragma unroll
      for (int ct = 0; ct < 2; ++ct)
#pragma unroll
        for (int r = 0; r < 4; ++r) h[rt][ct][r] = acc[rt][ct][r] + c_bout[ncol[ct]];
#pragma unroll
    for (int rt = 0; rt < 4; ++rt) {
      float s0[4] = {0, 0, 0, 0}, q0[4] = {0, 0, 0, 0};
#pragma unroll
      for (int ct = 0; ct < 2; ++ct)
#pragma unroll
        for (int r = 0; r < 4; ++r) { float v = h[rt][ct][r]; s0[r] += v; q0[r] = fmaf(v, v, q0[r]); }
#pragma unroll
      for (int r = 0; r < 4; ++r) {
        float a = s0[r], bq = q0[r];
        a += __shfl_xor(a, 1, 64); bq += __shfl_xor(bq, 1, 64);
        a += __shfl_xor(a, 2, 64); bq += __shfl_xor(bq, 2, 64);
        a += __shfl_xor(a, 4, 64); bq += __shfl_xor(bq, 4, 64);
        a += __shfl_xor(a, 8, 64); bq += __shfl_xor(bq, 8, 64);
        if (li == 0) { int row = rt * 16 + g * 4 + r; red[wid][row][0] = a; red[wid][row][1] = bq; }
      }
    }
    __syncthreads();
    if (t < 64) {
      float S = 0.f, Q = 0.f;
#pragma unroll
      for (int w = 0; w < 8; ++w) { S += red[w][t][0]; Q += red[w][t][1]; }
      float mean = S * (1.f / 256.f);
      float var = Q * (1.f / 256.f) - mean * mean;
      mr_s[t][0] = mean; mr_s[t][1] = rsqrtf(var + 1e-5f);
    }
    __syncthreads();
#pragma unroll
    for (int rt = 0; rt < 4; ++rt)
#pragma unroll
      for (int r = 0; r < 4; ++r) {
        int row = rt * 16 + g * 4 + r;
        float mean = mr_s[row][0], rstd = mr_s[row][1];
#pragma unroll
        for (int ct = 0; ct < 2; ++ct)
          out[(rowbase + row) * 256 + ncol[ct]] =
              (h[rt][ct][r] - mean) * rstd * c_lngf[ncol[ct]] + c_lnbf[ncol[ct]];
      }
  }
}

extern "C" void kernel_launch(void* const* d_in, const int* in_sizes, int n_in,
                              void* d_out, int out_size, void* d_ws, size_t ws_size,
                              hipStream_t stream) {
  const float* x    = (const float*)d_in[0];
  const int*   adj  = (const int*)d_in[1];
  const float* gdv  = (const float*)d_in[2];
  const float* Win  = (const float*)d_in[3];
  const float* bin  = (const float*)d_in[4];
  const float* Wout = (const float*)d_in[5];
  const float* bout = (const float*)d_in[6];
  const float* g1W  = (const float*)d_in[7];
  const float* g1b  = (const float*)d_in[8];
  const float* g2W  = (const float*)d_in[9];
  const float* g2b  = (const float*)d_in[10];
  const float* grW  = (const float*)d_in[11];
  const float* grb  = (const float*)d_in[12];
  const float* lngf = (const float*)d_in[13];
  const float* lnbf = (const float*)d_in[14];
  const float* Wf   = (const float*)d_in[15];
  const float* bfv  = (const float*)d_in[16];
  const float* Wt   = (const float*)d_in[17];
  const float* bt   = (const float*)d_in[18];
  const float* waf  = (const float*)d_in[19];
  const float* baf  = (const float*)d_in[20];
  const float* wat  = (const float*)d_in[21];
  const float* bat  = (const float*)d_in[22];
  const float* Wo   = (const float*)d_in[23];
  const float* bo   = (const float*)d_in[24];
  const float* lng  = (const float*)d_in[25];
  const float* lnb  = (const float*)d_in[26];
  float* out = (float*)d_out;

  float* W = (float*)d_ws;
  float* Tp = W;                                 // 2*256*256
  float* pb = W + 131072;                        // 512
  float* qb = W + 131584;
  float* rp = W + 132096;
  float* ub = W + 132608;
  float* cb = W + 133120;                        // 2 (+pad)
  unsigned short* Uws = (unsigned short*)(W + 133184);  // Win|Wout|M0|M1 swz bf16 (512KB)

  ta_kernel<<<512, 256, 0, stream>>>(gdv, g1W, g1b, g2W, g2b, grW, grb, Wt, bt, wat, Tp, pb, qb);
  tb_kernel<<<544, 256, 0, stream>>>(adj, Tp, pb, qb, bat, Wo, waf, baf, Wf, bfv, Win, Wout, rp, ub, cb, Uws);
  fused_kernel<<<512, 512, 0, stream>>>(x, rp, ub, cb, Uws, bin, bo, lng, lnb, bout, lngf, lnbf, out);
}

// Round 4
// 79.558 us; speedup vs baseline: 1.3255x; 1.0962x over previous
//
#include <hip/hip_runtime.h>
#include <hip/hip_bf16.h>

// GTAT integrated: B=8,N=4096,D=256,TD=64,GD=73,L=2 -> 32768 rows, row-parallel.
// TA (t,Tp,p,q) -> TB (beta,T_out,M=T_out@Wo swz, r',u,c, W swizzles)
//  -> fused (all 4 GEMM stages, h in registers, 64 rows/WG x 512 thr)
// R4: fix DPP ctrl to template constant (compile fix of R3).

typedef float f32x4 __attribute__((ext_vector_type(4)));
typedef short bf16x8 __attribute__((ext_vector_type(8)));

__device__ __forceinline__ unsigned short f2bf(float f) {
  unsigned int u = __builtin_bit_cast(unsigned int, f);
  u += 0x7FFFu + ((u >> 16) & 1u);   // round-to-nearest-even
  return (unsigned short)(u >> 16);
}
__device__ __forceinline__ float bf2f(unsigned short u) {
  return __builtin_bit_cast(float, (unsigned int)u << 16);
}
__device__ __forceinline__ float lrelu(float x) { return x > 0.f ? x : 0.01f * x; }

// ---- DPP 16-lane reduction (VALU only, no LDS pipe) ----
template <int CTRL>
__device__ __forceinline__ float dpp_ror_add(float v) {
  int s = __builtin_amdgcn_update_dpp(0, __builtin_bit_cast(int, v), CTRL, 0xf, 0xf, true);
  return v + __builtin_bit_cast(float, s);
}
__device__ __forceinline__ float sum16(float v) {   // all 16 lanes of each row get the sum
  v = dpp_ror_add<0x128>(v);  // row_ror:8
  v = dpp_ror_add<0x124>(v);  // row_ror:4
  v = dpp_ror_add<0x122>(v);  // row_ror:2
  v = dpp_ror_add<0x121>(v);  // row_ror:1
  return v;
}

// ---- block reduce helpers (256 threads, all must call) ----
__device__ __forceinline__ float block_sum(float v, float* s4, int t) {
  v = sum16(v);
  v += __shfl_xor(v, 16, 64);
  v += __shfl_xor(v, 32, 64);
  __syncthreads();
  if ((t & 63) == 0) s4[t >> 6] = v;
  __syncthreads();
  return s4[0] + s4[1] + s4[2] + s4[3];
}
__device__ __forceinline__ float block_max(float v, float* s4, int t) {
#pragma unroll
  for (int m = 1; m < 64; m <<= 1) v = fmaxf(v, __shfl_xor(v, m, 64));
  __syncthreads();
  if ((t & 63) == 0) s4[t >> 6] = v;
  __syncthreads();
  return fmaxf(fmaxf(s4[0], s4[1]), fmaxf(s4[2], s4[3]));
}

// B-operand swizzled layout: elem(k,n) -> ((((k>>5)*16 + (n>>4))*4 + ((k>>3)&3))*16 + (n&15))*8 + (k&7)
__device__ __forceinline__ int swz_off(int k, int n) {
  return ((((k >> 5) * 16 + (n >> 4)) * 4 + ((k >> 3) & 3)) * 16 + (n & 15)) * 8 + (k & 7);
}
// A-frag LDS byte offset for (k=n, row m in [0,64)), XOR-swizzled
__device__ __forceinline__ int alds_byte(int n, int m) {
  int grp = n >> 3;
  int base = (grp * 64 + m) * 16 + (n & 7) * 2;
  return base ^ ((grp & 7) << 4);
}

// ============ TA: t rows -> Tp rows + p,q  (grid 512 = L*256, 256 thr) ============
__global__ void ta_kernel(const float* __restrict__ gdv,
                          const float* __restrict__ g1W, const float* __restrict__ g1b,
                          const float* __restrict__ g2W, const float* __restrict__ g2b,
                          const float* __restrict__ grW, const float* __restrict__ grb,
                          const float* __restrict__ Wt, const float* __restrict__ bt,
                          const float* __restrict__ wat,
                          float* __restrict__ Tp, float* __restrict__ pb, float* __restrict__ qb) {
  int l = blockIdx.x >> 8, i = blockIdx.x & 255, t = threadIdx.x;
  __shared__ float gs[73], as_[64], ts[64], s4[4];
  float gv = (t < 73) ? gdv[i * 73 + t] : 0.f;
  float gsum = block_sum(gv, s4, t);
  if (t < 73) gs[t] = gv / (gsum + 1e-6f);
  __syncthreads();
  if (t < 64) {
    float a = g1b[t], gr = grb[t];
    for (int k = 0; k < 73; ++k) { float gk = gs[k]; a = fmaf(gk, g1W[k * 64 + t], a); gr = fmaf(gk, grW[k * 64 + t], gr); }
    as_[t] = fmaxf(a, 0.f);
    ts[t] = gr + g2b[t];
  }
  __syncthreads();
  float tv = 0.f;
  if (t < 64) {
    tv = ts[t];
    for (int k = 0; k < 64; ++k) tv = fmaf(as_[k], g2W[k * 64 + t], tv);
  }
  __syncthreads();
  if (t < 64) ts[t] = tv;
  __syncthreads();
  float tp = bt[l * 256 + t];
  for (int k = 0; k < 64; ++k) tp = fmaf(ts[k], Wt[(l * 64 + k) * 256 + t], tp);
  Tp[(l * 256 + i) * 256 + t] = tp;
  float pp = block_sum(tp * wat[l * 512 + t], s4, t);
  float qq = block_sum(tp * wat[l * 512 + 256 + t], s4, t);
  if (t == 0) { pb[l * 256 + i] = pp; qb[l * 256 + i] = qq; }
}

// ====== TB: beta,T_out row -> M row (swz bf16), r', u, c ; + W_in/W_out swizzles ======
__global__ void tb_kernel(const int* __restrict__ adj, const float* __restrict__ Tp,
                          const float* __restrict__ pb, const float* __restrict__ qb,
                          const float* __restrict__ batopo, const float* __restrict__ Wo,
                          const float* __restrict__ wafeat, const float* __restrict__ bafeat,
                          const float* __restrict__ Wf, const float* __restrict__ bfv,
                          const float* __restrict__ Win, const float* __restrict__ Wout,
                          float* __restrict__ rp, float* __restrict__ ub, float* __restrict__ cb,
                          unsigned short* __restrict__ Uws) {
  int b = blockIdx.x, t = threadIdx.x;
  if (b >= 512) {                               // weight swizzle blocks
    int bb = b - 512;
    const float* src = (bb < 16) ? Win : Wout;
    unsigned short* dst = Uws + ((bb < 16) ? 0 : 65536);
    int r0 = (bb & 15) * 16;
    for (int kk = 0; kk < 16; ++kk) {
      int k = r0 + kk;
      dst[swz_off(k, t)] = f2bf(src[k * 256 + t]);
    }
    return;
  }
  int l = b >> 8, i = b & 255;
  __shared__ float beta[256], tout[256], s4[4];
  float e = pb[l * 256 + i] + qb[l * 256 + t] + batopo[l];
  e = lrelu(e);
  if (adj[i * 256 + t] == 0) e = -1e9f;
  float mx = block_max(e, s4, t);
  float w = __expf(e - mx);
  float Z = block_sum(w, s4, t);
  beta[t] = w / Z;
  __syncthreads();
  float acc = 0.f;
  for (int j = 0; j < 256; ++j) acc = fmaf(beta[j], Tp[(l * 256 + j) * 256 + t], acc);
  tout[t] = acc;
  __syncthreads();
  const float* WoL = Wo + l * 65536;
  float macc = 0.f;
  for (int h2 = 0; h2 < 256; ++h2) macc = fmaf(tout[h2], WoL[h2 * 256 + t], macc);
  Uws[131072 + l * 65536 + swz_off(i, t)] = f2bf(macc);   // M_l row i
  const float* wf = wafeat + l * 512;
  float rsum = block_sum(tout[t] * wf[256 + t], s4, t);
  if (t == 0) rp[l * 256 + i] = rsum + bafeat[l];
  float usum = block_sum(Wf[(l * 256 + i) * 256 + t] * wf[t], s4, t);
  if (t == 0) ub[l * 256 + i] = usum;
  if (i == 0) {
    float csum = block_sum(bfv[l * 256 + t] * wf[t], s4, t);
    if (t == 0) cb[l] = csum;
  }
}

// ============ fused kernel: 4 GEMM stages, 512 WGs x 512 thr, 64 rows/WG ============
// wave tile = 64 rows x 32 cols (4x2 frags of 16x16x32). h in regs (32 f32/thread).
#define MFMA(A, B, C) __builtin_amdgcn_mfma_f32_16x16x32_bf16(A, B, C, 0, 0, 0)

__device__ __forceinline__ void kloop(const char* smc, const unsigned short* Bws,
                                      int wid, int lane, int li, int g, f32x4 acc[4][2]) {
  const bf16x8* Bw = (const bf16x8*)Bws + wid * 2 * 64 + lane;
  bf16x8 a0, a1, a2, a3, b0, b1;
  {
    int ab = ((g * 64 + li) * 16) ^ ((g & 7) << 4);
    b0 = Bw[0]; b1 = Bw[64];
    a0 = *(const bf16x8*)(smc + ab);
    a1 = *(const bf16x8*)(smc + ab + 256);
    a2 = *(const bf16x8*)(smc + ab + 512);
    a3 = *(const bf16x8*)(smc + ab + 768);
  }
#pragma unroll
  for (int kb = 0; kb < 8; ++kb) {
    bf16x8 na0, na1, na2, na3, nb0, nb1;
    if (kb < 7) {   // prefetch kb+1 while MFMAs of kb run
      nb0 = Bw[(kb + 1) * 1024];
      nb1 = Bw[(kb + 1) * 1024 + 64];
      int grp = (kb + 1) * 4 + g;
      int ab = ((grp * 64 + li) * 16) ^ ((grp & 7) << 4);
      na0 = *(const bf16x8*)(smc + ab);
      na1 = *(const bf16x8*)(smc + ab + 256);
      na2 = *(const bf16x8*)(smc + ab + 512);
      na3 = *(const bf16x8*)(smc + ab + 768);
    }
    acc[0][0] = MFMA(a0, b0, acc[0][0]);
    acc[1][0] = MFMA(a1, b0, acc[1][0]);
    acc[2][0] = MFMA(a2, b0, acc[2][0]);
    acc[3][0] = MFMA(a3, b0, acc[3][0]);
    acc[0][1] = MFMA(a0, b1, acc[0][1]);
    acc[1][1] = MFMA(a1, b1, acc[1][1]);
    acc[2][1] = MFMA(a2, b1, acc[2][1]);
    acc[3][1] = MFMA(a3, b1, acc[3][1]);
    if (kb < 7) { a0 = na0; a1 = na1; a2 = na2; a3 = na3; b0 = nb0; b1 = nb1; }
  }
}

// s = h . u + c per row, via DPP sum16 (all-lane) then per-wave partial to LDS
#define S_REDUCE(UBARR, CBV)                                                   \
  {                                                                            \
    float sarr[16];                                                            \
    _Pragma("unroll") for (int rt = 0; rt < 4; ++rt)                           \
      _Pragma("unroll") for (int r = 0; r < 4; ++r)                            \
        sarr[rt * 4 + r] = h[rt][0][r] * UBARR[ncol[0]] + h[rt][1][r] * UBARR[ncol[1]]; \
    _Pragma("unroll") for (int i = 0; i < 16; ++i) sarr[i] = sum16(sarr[i]);   \
    if (li == 0) {                                                             \
      _Pragma("unroll") for (int rt = 0; rt < 4; ++rt)                         \
        _Pragma("unroll") for (int r = 0; r < 4; ++r)                          \
          red[wid][rt * 16 + g * 4 + r][0] = sarr[rt * 4 + r];                 \
    }                                                                          \
    __syncthreads();                                                           \
    if (t < 64) {                                                              \
      float S = 0.f;                                                           \
      _Pragma("unroll") for (int w = 0; w < 8; ++w) S += red[w][t][0];         \
      row_s[t] = S + (CBV);                                                    \
    }                                                                          \
    __syncthreads();                                                           \
  }

__global__ __launch_bounds__(512, 4) void fused_kernel(
    const float* __restrict__ x,
    const float* __restrict__ rp, const float* __restrict__ ub, const float* __restrict__ cbp,
    const unsigned short* __restrict__ Uws,
    const float* __restrict__ bin, const float* __restrict__ bo,
    const float* __restrict__ lng, const float* __restrict__ lnb,
    const float* __restrict__ bout, const float* __restrict__ lngf, const float* __restrict__ lnbf,
    float* __restrict__ out) {
  __shared__ unsigned short alds[16384];     // 32KB A fragments
  __shared__ float c_bin[256], c_bout[256], c_lngf[256], c_lnbf[256];
  __shared__ float c_ub[2][256], c_bo[2][256], c_lng[2][256], c_lnb[2][256], c_rp[2][256];
  __shared__ float red[8][64][2];
  __shared__ float row_s[64], invz_s[64];
  __shared__ float mr_s[64][2];
  __shared__ float scal_s[4];                // Rm0, Rm1, cb0, cb1
  char* smc = (char*)alds;

  const int wg = blockIdx.x, t = threadIdx.x;
  const int wid = t >> 6, lane = t & 63, li = lane & 15, g = lane >> 4;
  const int rowbase = wg * 64;
  int ncol[2]; ncol[0] = wid * 32 + li; ncol[1] = wid * 32 + 16 + li;

  // constants -> LDS
  if (t < 256) {
    c_bin[t] = bin[t]; c_ub[0][t] = ub[t]; c_bo[0][t] = bo[t];
    c_lng[0][t] = lng[t]; c_lnb[0][t] = lnb[t]; c_rp[0][t] = rp[t];
  } else {
    int u = t - 256;
    c_bout[u] = bout[u]; c_lngf[u] = lngf[u]; c_lnbf[u] = lnbf[u];
    c_ub[1][u] = ub[256 + u]; c_bo[1][u] = bo[256 + u];
    c_lng[1][u] = lng[256 + u]; c_lnb[1][u] = lnb[256 + u]; c_rp[1][u] = rp[256 + u];
  }
  if (t == 0) { scal_s[2] = cbp[0]; scal_s[3] = cbp[1]; }

  // stage x -> alds (bf16, A-frag layout); coalesced float4 global reads
#pragma unroll
  for (int it = 0; it < 8; ++it) {
    int flat = it * 2048 + t * 4;
    int m = flat >> 8, col = flat & 255;
    const float4 xv = *(const float4*)(x + (rowbase + m) * 256 + col);
    ushort4 pk; pk.x = f2bf(xv.x); pk.y = f2bf(xv.y); pk.z = f2bf(xv.z); pk.w = f2bf(xv.w);
    *(ushort4*)(smc + alds_byte(col, m)) = pk;
  }
  __syncthreads();
  if (wid < 2) {   // Rm_l = max_f r'_l (once, 2 waves; shfl ok here)
    float m2 = fmaxf(fmaxf(c_rp[wid][lane], c_rp[wid][lane + 64]),
                     fmaxf(c_rp[wid][lane + 128], c_rp[wid][lane + 192]));
#pragma unroll
    for (int mm = 1; mm < 64; mm <<= 1) m2 = fmaxf(m2, __shfl_xor(m2, mm, 64));
    if (lane == 0) scal_s[wid] = m2;
  }

  float h[4][2][4];

  // ---- stage 0: h0 = x@Win + bin ; s0 ----
  {
    f32x4 acc[4][2];
#pragma unroll
    for (int a = 0; a < 4; ++a)
#pragma unroll
      for (int c = 0; c < 2; ++c) { f32x4 z = {0.f, 0.f, 0.f, 0.f}; acc[a][c] = z; }
    kloop(smc, Uws, wid, lane, li, g, acc);
#pragma unroll
    for (int rt = 0; rt < 4; ++rt)
#pragma unroll
      for (int ct = 0; ct < 2; ++ct)
#pragma unroll
        for (int r = 0; r < 4; ++r) h[rt][ct][r] = acc[rt][ct][r] + c_bin[ncol[ct]];
    S_REDUCE(c_ub[0], scal_s[2]);
  }

  // ---- layers ----
#pragma unroll 1
  for (int l = 0; l < 2; ++l) {
    // alpha (un-normalized bf16) -> alds via b128 writes; Z partials
    {
      int row = t & 63;                     // == lane
      float sm = row_s[row];
      float mx = lrelu(sm + scal_s[l]);     // exact max: lrelu monotone
      float z = 0.f;
#pragma unroll
      for (int it = 0; it < 4; ++it) {
        int grp = it * 8 + wid;
        float w0 = __expf(lrelu(sm + c_rp[l][grp * 8 + 0]) - mx);
        float w1 = __expf(lrelu(sm + c_rp[l][grp * 8 + 1]) - mx);
        float w2 = __expf(lrelu(sm + c_rp[l][grp * 8 + 2]) - mx);
        float w3 = __expf(lrelu(sm + c_rp[l][grp * 8 + 3]) - mx);
        float w4 = __expf(lrelu(sm + c_rp[l][grp * 8 + 4]) - mx);
        float w5 = __expf(lrelu(sm + c_rp[l][grp * 8 + 5]) - mx);
        float w6 = __expf(lrelu(sm + c_rp[l][grp * 8 + 6]) - mx);
        float w7 = __expf(lrelu(sm + c_rp[l][grp * 8 + 7]) - mx);
        unsigned short u0 = f2bf(w0), u1 = f2bf(w1), u2 = f2bf(w2), u3 = f2bf(w3);
        unsigned short u4 = f2bf(w4), u5 = f2bf(w5), u6 = f2bf(w6), u7 = f2bf(w7);
        z += bf2f(u0) + bf2f(u1) + bf2f(u2) + bf2f(u3) +
             bf2f(u4) + bf2f(u5) + bf2f(u6) + bf2f(u7);
        uint4 pk;
        pk.x = (unsigned int)u0 | ((unsigned int)u1 << 16);
        pk.y = (unsigned int)u2 | ((unsigned int)u3 << 16);
        pk.z = (unsigned int)u4 | ((unsigned int)u5 << 16);
        pk.w = (unsigned int)u6 | ((unsigned int)u7 << 16);
        int byte = ((grp * 64 + row) * 16) ^ ((grp & 7) << 4);
        *(uint4*)(smc + byte) = pk;
      }
      red[wid][row][0] = z;
    }
    __syncthreads();
    if (t < 64) {
      float Z = 0.f;
#pragma unroll
      for (int w = 0; w < 8; ++w) Z += red[w][t][0];
      invz_s[t] = 1.f / Z;
    }
    __syncthreads();

    f32x4 acc[4][2];
#pragma unroll
    for (int a = 0; a < 4; ++a)
#pragma unroll
      for (int c = 0; c < 2; ++c) { f32x4 z = {0.f, 0.f, 0.f, 0.f}; acc[a][c] = z; }
    kloop(smc, Uws + 131072 + l * 65536, wid, lane, li, g, acc);

    // h = LN(acc/Z + bo + h)
#pragma unroll
    for (int rt = 0; rt < 4; ++rt)
#pragma unroll
      for (int r = 0; r < 4; ++r) {
        int row = rt * 16 + g * 4 + r;
        float iz = invz_s[row];
#pragma unroll
        for (int ct = 0; ct < 2; ++ct)
          h[rt][ct][r] = fmaf(acc[rt][ct][r], iz, c_bo[l][ncol[ct]] + h[rt][ct][r]);
      }
    {  // LN stats via DPP
      float sA[16], sQ[16];
#pragma unroll
      for (int rt = 0; rt < 4; ++rt)
#pragma unroll
        for (int r = 0; r < 4; ++r) {
          float a0 = h[rt][0][r], a1 = h[rt][1][r];
          sA[rt * 4 + r] = a0 + a1;
          sQ[rt * 4 + r] = a0 * a0 + a1 * a1;
        }
#pragma unroll
      for (int i = 0; i < 16; ++i) { sA[i] = sum16(sA[i]); sQ[i] = sum16(sQ[i]); }
      if (li == 0) {
#pragma unroll
        for (int rt = 0; rt < 4; ++rt)
#pragma unroll
          for (int r = 0; r < 4; ++r) {
            int row = rt * 16 + g * 4 + r;
            red[wid][row][0] = sA[rt * 4 + r]; red[wid][row][1] = sQ[rt * 4 + r];
          }
      }
    }
    __syncthreads();
    if (t < 64) {
      float S = 0.f, Q = 0.f;
#pragma unroll
      for (int w = 0; w < 8; ++w) { S += red[w][t][0]; Q += red[w][t][1]; }
      float mean = S * (1.f / 256.f);
      float var = Q * (1.f / 256.f) - mean * mean;
      mr_s[t][0] = mean; mr_s[t][1] = rsqrtf(var + 1e-5f);
    }
    __syncthreads();
#pragma unroll
    for (int rt = 0; rt < 4; ++rt)
#pragma unroll
      for (int r = 0; r < 4; ++r) {
        int row = rt * 16 + g * 4 + r;
        float mean = mr_s[row][0], rstd = mr_s[row][1];
#pragma unroll
        for (int ct = 0; ct < 2; ++ct)
          h[rt][ct][r] = (h[rt][ct][r] - mean) * rstd * c_lng[l][ncol[ct]] + c_lnb[l][ncol[ct]];
      }
    if (l == 0) S_REDUCE(c_ub[1], scal_s[3]);
  }

  // ---- stage 3: out = LN(h@Wout + bout) ----
#pragma unroll
  for (int rt = 0; rt < 4; ++rt)
#pragma unroll
    for (int ct = 0; ct < 2; ++ct)
#pragma unroll
      for (int r = 0; r < 4; ++r) {
        int row = rt * 16 + g * 4 + r;
        *(unsigned short*)(smc + alds_byte(ncol[ct], row)) = f2bf(h[rt][ct][r]);
      }
  __syncthreads();
  {
    f32x4 acc[4][2];
#pragma unroll
    for (int a = 0; a < 4; ++a)
#pragma unroll
      for (int c = 0; c < 2; ++c) { f32x4 z = {0.f, 0.f, 0.f, 0.f}; acc[a][c] = z; }
    kloop(smc, Uws + 65536, wid, lane, li, g, acc);
#pragma unroll
    for (int rt = 0; rt < 4; ++rt)
#pragma unroll
      for (int ct = 0; ct < 2; ++ct)
#pragma unroll
        for (int r = 0; r < 4; ++r) h[rt][ct][r] = acc[rt][ct][r] + c_bout[ncol[ct]];
    {  // LN stats via DPP
      float sA[16], sQ[16];
#pragma unroll
      for (int rt = 0; rt < 4; ++rt)
#pragma unroll
        for (int r = 0; r < 4; ++r) {
          float a0 = h[rt][0][r], a1 = h[rt][1][r];
          sA[rt * 4 + r] = a0 + a1;
          sQ[rt * 4 + r] = a0 * a0 + a1 * a1;
        }
#pragma unroll
      for (int i = 0; i < 16; ++i) { sA[i] = sum16(sA[i]); sQ[i] = sum16(sQ[i]); }
      if (li == 0) {
#pragma unroll
        for (int rt = 0; rt < 4; ++rt)
#pragma unroll
          for (int r = 0; r < 4; ++r) {
            int row = rt * 16 + g * 4 + r;
            red[wid][row][0] = sA[rt * 4 + r]; red[wid][row][1] = sQ[rt * 4 + r];
          }
      }
    }
    __syncthreads();
    if (t < 64) {
      float S = 0.f, Q = 0.f;
#pragma unroll
      for (int w = 0; w < 8; ++w) { S += red[w][t][0]; Q += red[w][t][1]; }
      float mean = S * (1.f / 256.f);
      float var = Q * (1.f / 256.f) - mean * mean;
      mr_s[t][0] = mean; mr_s[t][1] = rsqrtf(var + 1e-5f);
    }
    __syncthreads();
#pragma unroll
    for (int rt = 0; rt < 4; ++rt)
#pragma unroll
      for (int r = 0; r < 4; ++r) {
        int row = rt * 16 + g * 4 + r;
        float mean = mr_s[row][0], rstd = mr_s[row][1];
#pragma unroll
        for (int ct = 0; ct < 2; ++ct)
          out[(rowbase + row) * 256 + ncol[ct]] =
              (h[rt][ct][r] - mean) * rstd * c_lngf[ncol[ct]] + c_lnbf[ncol[ct]];
      }
  }
}

extern "C" void kernel_launch(void* const* d_in, const int* in_sizes, int n_in,
                              void* d_out, int out_size, void* d_ws, size_t ws_size,
                              hipStream_t stream) {
  const float* x    = (const float*)d_in[0];
  const int*   adj  = (const int*)d_in[1];
  const float* gdv  = (const float*)d_in[2];
  const float* Win  = (const float*)d_in[3];
  const float* bin  = (const float*)d_in[4];
  const float* Wout = (const float*)d_in[5];
  const float* bout = (const float*)d_in[6];
  const float* g1W  = (const float*)d_in[7];
  const float* g1b  = (const float*)d_in[8];
  const float* g2W  = (const float*)d_in[9];
  const float* g2b  = (const float*)d_in[10];
  const float* grW  = (const float*)d_in[11];
  const float* grb  = (const float*)d_in[12];
  const float* lngf = (const float*)d_in[13];
  const float* lnbf = (const float*)d_in[14];
  const float* Wf   = (const float*)d_in[15];
  const float* bfv  = (const float*)d_in[16];
  const float* Wt   = (const float*)d_in[17];
  const float* bt   = (const float*)d_in[18];
  const float* waf  = (const float*)d_in[19];
  const float* baf  = (const float*)d_in[20];
  const float* wat  = (const float*)d_in[21];
  const float* bat  = (const float*)d_in[22];
  const float* Wo   = (const float*)d_in[23];
  const float* bo   = (const float*)d_in[24];
  const float* lng  = (const float*)d_in[25];
  const float* lnb  = (const float*)d_in[26];
  float* out = (float*)d_out;

  float* W = (float*)d_ws;
  float* Tp = W;                                 // 2*256*256
  float* pb = W + 131072;                        // 512
  float* qb = W + 131584;
  float* rp = W + 132096;
  float* ub = W + 132608;
  float* cb = W + 133120;                        // 2 (+pad)
  unsigned short* Uws = (unsigned short*)(W + 133184);  // Win|Wout|M0|M1 swz bf16 (512KB)

  ta_kernel<<<512, 256, 0, stream>>>(gdv, g1W, g1b, g2W, g2b, grW, grb, Wt, bt, wat, Tp, pb, qb);
  tb_kernel<<<544, 256, 0, stream>>>(adj, Tp, pb, qb, bat, Wo, waf, baf, Wf, bfv, Win, Wout, rp, ub, cb, Uws);
  fused_kernel<<<512, 512, 0, stream>>>(x, rp, ub, cb, Uws, bin, bo, lng, lnb, bout, lngf, lnbf, out);
}

// Round 5
// 75.475 us; speedup vs baseline: 1.3972x; 1.0541x over previous
//
#include <hip/hip_runtime.h>
#include <hip/hip_bf16.h>

// GTAT integrated: B=8,N=4096,D=256,TD=64,GD=73,L=2 -> 32768 rows, row-parallel.
// TA (t,Tp,p,q) -> TB (beta,T_out,M=T_out@Wo swz, r',u,c, W swizzles)
//  -> fused (all 4 GEMM stages, h in registers, 64 rows/WG x 512 thr)
// R5: kill scratch spills — pad LDS >54.6KB so only 2 blocks/CU fit => VGPR budget 128;
//     drop A-prefetch (peak-pressure), keep 1-deep B prefetch.

typedef float f32x4 __attribute__((ext_vector_type(4)));
typedef short bf16x8 __attribute__((ext_vector_type(8)));

__device__ __forceinline__ unsigned short f2bf(float f) {
  unsigned int u = __builtin_bit_cast(unsigned int, f);
  u += 0x7FFFu + ((u >> 16) & 1u);   // round-to-nearest-even
  return (unsigned short)(u >> 16);
}
__device__ __forceinline__ float bf2f(unsigned short u) {
  return __builtin_bit_cast(float, (unsigned int)u << 16);
}
__device__ __forceinline__ float lrelu(float x) { return x > 0.f ? x : 0.01f * x; }

// ---- DPP 16-lane reduction (VALU only, no LDS pipe) ----
template <int CTRL>
__device__ __forceinline__ float dpp_ror_add(float v) {
  int s = __builtin_amdgcn_update_dpp(0, __builtin_bit_cast(int, v), CTRL, 0xf, 0xf, true);
  return v + __builtin_bit_cast(float, s);
}
__device__ __forceinline__ float sum16(float v) {   // all 16 lanes of each row get the sum
  v = dpp_ror_add<0x128>(v);  // row_ror:8
  v = dpp_ror_add<0x124>(v);  // row_ror:4
  v = dpp_ror_add<0x122>(v);  // row_ror:2
  v = dpp_ror_add<0x121>(v);  // row_ror:1
  return v;
}

// ---- block reduce helpers (256 threads, all must call) ----
__device__ __forceinline__ float block_sum(float v, float* s4, int t) {
  v = sum16(v);
  v += __shfl_xor(v, 16, 64);
  v += __shfl_xor(v, 32, 64);
  __syncthreads();
  if ((t & 63) == 0) s4[t >> 6] = v;
  __syncthreads();
  return s4[0] + s4[1] + s4[2] + s4[3];
}
__device__ __forceinline__ float block_max(float v, float* s4, int t) {
#pragma unroll
  for (int m = 1; m < 64; m <<= 1) v = fmaxf(v, __shfl_xor(v, m, 64));
  __syncthreads();
  if ((t & 63) == 0) s4[t >> 6] = v;
  __syncthreads();
  return fmaxf(fmaxf(s4[0], s4[1]), fmaxf(s4[2], s4[3]));
}

// B-operand swizzled layout: elem(k,n) -> ((((k>>5)*16 + (n>>4))*4 + ((k>>3)&3))*16 + (n&15))*8 + (k&7)
__device__ __forceinline__ int swz_off(int k, int n) {
  return ((((k >> 5) * 16 + (n >> 4)) * 4 + ((k >> 3) & 3)) * 16 + (n & 15)) * 8 + (k & 7);
}
// A-frag LDS byte offset for (k=n, row m in [0,64)), XOR-swizzled
__device__ __forceinline__ int alds_byte(int n, int m) {
  int grp = n >> 3;
  int base = (grp * 64 + m) * 16 + (n & 7) * 2;
  return base ^ ((grp & 7) << 4);
}

// ============ TA: t rows -> Tp rows + p,q  (grid 512 = L*256, 256 thr) ============
__global__ void ta_kernel(const float* __restrict__ gdv,
                          const float* __restrict__ g1W, const float* __restrict__ g1b,
                          const float* __restrict__ g2W, const float* __restrict__ g2b,
                          const float* __restrict__ grW, const float* __restrict__ grb,
                          const float* __restrict__ Wt, const float* __restrict__ bt,
                          const float* __restrict__ wat,
                          float* __restrict__ Tp, float* __restrict__ pb, float* __restrict__ qb) {
  int l = blockIdx.x >> 8, i = blockIdx.x & 255, t = threadIdx.x;
  __shared__ float gs[73], as_[64], ts[64], s4[4];
  float gv = (t < 73) ? gdv[i * 73 + t] : 0.f;
  float gsum = block_sum(gv, s4, t);
  if (t < 73) gs[t] = gv / (gsum + 1e-6f);
  __syncthreads();
  if (t < 64) {
    float a = g1b[t], gr = grb[t];
    for (int k = 0; k < 73; ++k) { float gk = gs[k]; a = fmaf(gk, g1W[k * 64 + t], a); gr = fmaf(gk, grW[k * 64 + t], gr); }
    as_[t] = fmaxf(a, 0.f);
    ts[t] = gr + g2b[t];
  }
  __syncthreads();
  float tv = 0.f;
  if (t < 64) {
    tv = ts[t];
    for (int k = 0; k < 64; ++k) tv = fmaf(as_[k], g2W[k * 64 + t], tv);
  }
  __syncthreads();
  if (t < 64) ts[t] = tv;
  __syncthreads();
  float tp = bt[l * 256 + t];
  for (int k = 0; k < 64; ++k) tp = fmaf(ts[k], Wt[(l * 64 + k) * 256 + t], tp);
  Tp[(l * 256 + i) * 256 + t] = tp;
  float pp = block_sum(tp * wat[l * 512 + t], s4, t);
  float qq = block_sum(tp * wat[l * 512 + 256 + t], s4, t);
  if (t == 0) { pb[l * 256 + i] = pp; qb[l * 256 + i] = qq; }
}

// ====== TB: beta,T_out row -> M row (swz bf16), r', u, c ; + W_in/W_out swizzles ======
__global__ void tb_kernel(const int* __restrict__ adj, const float* __restrict__ Tp,
                          const float* __restrict__ pb, const float* __restrict__ qb,
                          const float* __restrict__ batopo, const float* __restrict__ Wo,
                          const float* __restrict__ wafeat, const float* __restrict__ bafeat,
                          const float* __restrict__ Wf, const float* __restrict__ bfv,
                          const float* __restrict__ Win, const float* __restrict__ Wout,
                          float* __restrict__ rp, float* __restrict__ ub, float* __restrict__ cb,
                          unsigned short* __restrict__ Uws) {
  int b = blockIdx.x, t = threadIdx.x;
  if (b >= 512) {                               // weight swizzle blocks
    int bb = b - 512;
    const float* src = (bb < 16) ? Win : Wout;
    unsigned short* dst = Uws + ((bb < 16) ? 0 : 65536);
    int r0 = (bb & 15) * 16;
    for (int kk = 0; kk < 16; ++kk) {
      int k = r0 + kk;
      dst[swz_off(k, t)] = f2bf(src[k * 256 + t]);
    }
    return;
  }
  int l = b >> 8, i = b & 255;
  __shared__ float beta[256], tout[256], s4[4];
  float e = pb[l * 256 + i] + qb[l * 256 + t] + batopo[l];
  e = lrelu(e);
  if (adj[i * 256 + t] == 0) e = -1e9f;
  float mx = block_max(e, s4, t);
  float w = __expf(e - mx);
  float Z = block_sum(w, s4, t);
  beta[t] = w / Z;
  __syncthreads();
  float acc = 0.f;
  for (int j = 0; j < 256; ++j) acc = fmaf(beta[j], Tp[(l * 256 + j) * 256 + t], acc);
  tout[t] = acc;
  __syncthreads();
  const float* WoL = Wo + l * 65536;
  float macc = 0.f;
  for (int h2 = 0; h2 < 256; ++h2) macc = fmaf(tout[h2], WoL[h2 * 256 + t], macc);
  Uws[131072 + l * 65536 + swz_off(i, t)] = f2bf(macc);   // M_l row i
  const float* wf = wafeat + l * 512;
  float rsum = block_sum(tout[t] * wf[256 + t], s4, t);
  if (t == 0) rp[l * 256 + i] = rsum + bafeat[l];
  float usum = block_sum(Wf[(l * 256 + i) * 256 + t] * wf[t], s4, t);
  if (t == 0) ub[l * 256 + i] = usum;
  if (i == 0) {
    float csum = block_sum(bfv[l * 256 + t] * wf[t], s4, t);
    if (t == 0) cb[l] = csum;
  }
}

// ============ fused kernel: 4 GEMM stages, 512 WGs x 512 thr, 64 rows/WG ============
// wave tile = 64 rows x 32 cols (4x2 frags of 16x16x32). h in regs (32 f32/thread).
#define MFMA(A, B, C) __builtin_amdgcn_mfma_f32_16x16x32_bf16(A, B, C, 0, 0, 0)

__device__ __forceinline__ void kloop(const char* smc, const unsigned short* Bws,
                                      int wid, int lane, int li, int g, f32x4 acc[4][2]) {
  const bf16x8* Bw = (const bf16x8*)Bws + wid * 2 * 64 + lane;
  bf16x8 b0 = Bw[0], b1 = Bw[64];
#pragma unroll
  for (int kb = 0; kb < 8; ++kb) {
    bf16x8 nb0, nb1;
    if (kb < 7) {            // 1-deep B prefetch covers ~200cy L2 latency
      nb0 = Bw[(kb + 1) * 1024];
      nb1 = Bw[(kb + 1) * 1024 + 64];
    }
    int grp = kb * 4 + g;
    int ab = ((grp * 64 + li) * 16) ^ ((grp & 7) << 4);
    bf16x8 a0 = *(const bf16x8*)(smc + ab);
    bf16x8 a1 = *(const bf16x8*)(smc + ab + 256);
    bf16x8 a2 = *(const bf16x8*)(smc + ab + 512);
    bf16x8 a3 = *(const bf16x8*)(smc + ab + 768);
    acc[0][0] = MFMA(a0, b0, acc[0][0]);
    acc[1][0] = MFMA(a1, b0, acc[1][0]);
    acc[2][0] = MFMA(a2, b0, acc[2][0]);
    acc[3][0] = MFMA(a3, b0, acc[3][0]);
    acc[0][1] = MFMA(a0, b1, acc[0][1]);
    acc[1][1] = MFMA(a1, b1, acc[1][1]);
    acc[2][1] = MFMA(a2, b1, acc[2][1]);
    acc[3][1] = MFMA(a3, b1, acc[3][1]);
    if (kb < 7) { b0 = nb0; b1 = nb1; }
  }
}

// s = h . u + c per row, via DPP sum16 (all-lane) then per-wave partial to LDS
#define S_REDUCE(UBARR, CBV)                                                   \
  {                                                                            \
    float sarr[16];                                                            \
    _Pragma("unroll") for (int rt = 0; rt < 4; ++rt)                           \
      _Pragma("unroll") for (int r = 0; r < 4; ++r)                            \
        sarr[rt * 4 + r] = h[rt][0][r] * UBARR[ncol[0]] + h[rt][1][r] * UBARR[ncol[1]]; \
    _Pragma("unroll") for (int i = 0; i < 16; ++i) sarr[i] = sum16(sarr[i]);   \
    if (li == 0) {                                                             \
      _Pragma("unroll") for (int rt = 0; rt < 4; ++rt)                         \
        _Pragma("unroll") for (int r = 0; r < 4; ++r)                          \
          red[wid][rt * 16 + g * 4 + r][0] = sarr[rt * 4 + r];                 \
    }                                                                          \
    __syncthreads();                                                           \
    if (t < 64) {                                                              \
      float S = 0.f;                                                           \
      _Pragma("unroll") for (int w = 0; w < 8; ++w) S += red[w][t][0];         \
      row_s[t] = S + (CBV);                                                    \
    }                                                                          \
    __syncthreads();                                                           \
  }

__global__ __launch_bounds__(512, 4) void fused_kernel(
    const float* __restrict__ x,
    const float* __restrict__ rp, const float* __restrict__ ub, const float* __restrict__ cbp,
    const unsigned short* __restrict__ Uws,
    const float* __restrict__ bin, const float* __restrict__ bo,
    const float* __restrict__ lng, const float* __restrict__ lnb,
    const float* __restrict__ bout, const float* __restrict__ lngf, const float* __restrict__ lnbf,
    float* __restrict__ out) {
  // alds padded 16384->18432 shorts: total LDS 56.3KB > 160/3 KB => only 2 blocks/CU fit
  // by LDS => register allocator budget = 4 waves/EU = 128 VGPR => no scratch spills.
  __shared__ unsigned short alds[18432];
  __shared__ float c_bin[256], c_bout[256], c_lngf[256], c_lnbf[256];
  __shared__ float c_ub[2][256], c_bo[2][256], c_lng[2][256], c_lnb[2][256], c_rp[2][256];
  __shared__ float red[8][64][2];
  __shared__ float row_s[64], invz_s[64];
  __shared__ float mr_s[64][2];
  __shared__ float scal_s[4];                // Rm0, Rm1, cb0, cb1
  char* smc = (char*)alds;

  const int wg = blockIdx.x, t = threadIdx.x;
  const int wid = t >> 6, lane = t & 63, li = lane & 15, g = lane >> 4;
  const int rowbase = wg * 64;
  int ncol[2]; ncol[0] = wid * 32 + li; ncol[1] = wid * 32 + 16 + li;

  // constants -> LDS
  if (t < 256) {
    c_bin[t] = bin[t]; c_ub[0][t] = ub[t]; c_bo[0][t] = bo[t];
    c_lng[0][t] = lng[t]; c_lnb[0][t] = lnb[t]; c_rp[0][t] = rp[t];
  } else {
    int u = t - 256;
    c_bout[u] = bout[u]; c_lngf[u] = lngf[u]; c_lnbf[u] = lnbf[u];
    c_ub[1][u] = ub[256 + u]; c_bo[1][u] = bo[256 + u];
    c_lng[1][u] = lng[256 + u]; c_lnb[1][u] = lnb[256 + u]; c_rp[1][u] = rp[256 + u];
  }
  if (t == 0) { scal_s[2] = cbp[0]; scal_s[3] = cbp[1]; }

  // stage x -> alds (bf16, A-frag layout); coalesced float4 global reads
#pragma unroll
  for (int it = 0; it < 8; ++it) {
    int flat = it * 2048 + t * 4;
    int m = flat >> 8, col = flat & 255;
    const float4 xv = *(const float4*)(x + (rowbase + m) * 256 + col);
    ushort4 pk; pk.x = f2bf(xv.x); pk.y = f2bf(xv.y); pk.z = f2bf(xv.z); pk.w = f2bf(xv.w);
    *(ushort4*)(smc + alds_byte(col, m)) = pk;
  }
  __syncthreads();
  if (wid < 2) {   // Rm_l = max_f r'_l (once, 2 waves; shfl ok here)
    float m2 = fmaxf(fmaxf(c_rp[wid][lane], c_rp[wid][lane + 64]),
                     fmaxf(c_rp[wid][lane + 128], c_rp[wid][lane + 192]));
#pragma unroll
    for (int mm = 1; mm < 64; mm <<= 1) m2 = fmaxf(m2, __shfl_xor(m2, mm, 64));
    if (lane == 0) scal_s[wid] = m2;
  }

  float h[4][2][4];

  // ---- stage 0: h0 = x@Win + bin ; s0 ----
  {
    f32x4 acc[4][2];
#pragma unroll
    for (int a = 0; a < 4; ++a)
#pragma unroll
      for (int c = 0; c < 2; ++c) { f32x4 z = {0.f, 0.f, 0.f, 0.f}; acc[a][c] = z; }
    kloop(smc, Uws, wid, lane, li, g, acc);
#pragma unroll
    for (int rt = 0; rt < 4; ++rt)
#pragma unroll
      for (int ct = 0; ct < 2; ++ct)
#pragma unroll
        for (int r = 0; r < 4; ++r) h[rt][ct][r] = acc[rt][ct][r] + c_bin[ncol[ct]];
    S_REDUCE(c_ub[0], scal_s[2]);
  }

  // ---- layers ----
#pragma unroll 1
  for (int l = 0; l < 2; ++l) {
    // alpha (un-normalized bf16) -> alds via b128 writes; Z partials
    {
      int row = t & 63;                     // == lane
      float sm = row_s[row];
      float mx = lrelu(sm + scal_s[l]);     // exact max: lrelu monotone
      float z = 0.f;
#pragma unroll
      for (int it = 0; it < 4; ++it) {
        int grp = it * 8 + wid;
        float w0 = __expf(lrelu(sm + c_rp[l][grp * 8 + 0]) - mx);
        float w1 = __expf(lrelu(sm + c_rp[l][grp * 8 + 1]) - mx);
        float w2 = __expf(lrelu(sm + c_rp[l][grp * 8 + 2]) - mx);
        float w3 = __expf(lrelu(sm + c_rp[l][grp * 8 + 3]) - mx);
        float w4 = __expf(lrelu(sm + c_rp[l][grp * 8 + 4]) - mx);
        float w5 = __expf(lrelu(sm + c_rp[l][grp * 8 + 5]) - mx);
        float w6 = __expf(lrelu(sm + c_rp[l][grp * 8 + 6]) - mx);
        float w7 = __expf(lrelu(sm + c_rp[l][grp * 8 + 7]) - mx);
        unsigned short u0 = f2bf(w0), u1 = f2bf(w1), u2 = f2bf(w2), u3 = f2bf(w3);
        unsigned short u4 = f2bf(w4), u5 = f2bf(w5), u6 = f2bf(w6), u7 = f2bf(w7);
        z += bf2f(u0) + bf2f(u1) + bf2f(u2) + bf2f(u3) +
             bf2f(u4) + bf2f(u5) + bf2f(u6) + bf2f(u7);
        uint4 pk;
        pk.x = (unsigned int)u0 | ((unsigned int)u1 << 16);
        pk.y = (unsigned int)u2 | ((unsigned int)u3 << 16);
        pk.z = (unsigned int)u4 | ((unsigned int)u5 << 16);
        pk.w = (unsigned int)u6 | ((unsigned int)u7 << 16);
        int byte = ((grp * 64 + row) * 16) ^ ((grp & 7) << 4);
        *(uint4*)(smc + byte) = pk;
      }
      red[wid][row][0] = z;
    }
    __syncthreads();
    if (t < 64) {
      float Z = 0.f;
#pragma unroll
      for (int w = 0; w < 8; ++w) Z += red[w][t][0];
      invz_s[t] = 1.f / Z;
    }
    __syncthreads();

    f32x4 acc[4][2];
#pragma unroll
    for (int a = 0; a < 4; ++a)
#pragma unroll
      for (int c = 0; c < 2; ++c) { f32x4 z = {0.f, 0.f, 0.f, 0.f}; acc[a][c] = z; }
    kloop(smc, Uws + 131072 + l * 65536, wid, lane, li, g, acc);

    // h = LN(acc/Z + bo + h)
#pragma unroll
    for (int rt = 0; rt < 4; ++rt)
#pragma unroll
      for (int r = 0; r < 4; ++r) {
        int row = rt * 16 + g * 4 + r;
        float iz = invz_s[row];
#pragma unroll
        for (int ct = 0; ct < 2; ++ct)
          h[rt][ct][r] = fmaf(acc[rt][ct][r], iz, c_bo[l][ncol[ct]] + h[rt][ct][r]);
      }
    {  // LN stats via DPP
      float sA[16], sQ[16];
#pragma unroll
      for (int rt = 0; rt < 4; ++rt)
#pragma unroll
        for (int r = 0; r < 4; ++r) {
          float a0 = h[rt][0][r], a1 = h[rt][1][r];
          sA[rt * 4 + r] = a0 + a1;
          sQ[rt * 4 + r] = a0 * a0 + a1 * a1;
        }
#pragma unroll
      for (int i = 0; i < 16; ++i) { sA[i] = sum16(sA[i]); sQ[i] = sum16(sQ[i]); }
      if (li == 0) {
#pragma unroll
        for (int rt = 0; rt < 4; ++rt)
#pragma unroll
          for (int r = 0; r < 4; ++r) {
            int row = rt * 16 + g * 4 + r;
            red[wid][row][0] = sA[rt * 4 + r]; red[wid][row][1] = sQ[rt * 4 + r];
          }
      }
    }
    __syncthreads();
    if (t < 64) {
      float S = 0.f, Q = 0.f;
#pragma unroll
      for (int w = 0; w < 8; ++w) { S += red[w][t][0]; Q += red[w][t][1]; }
      float mean = S * (1.f / 256.f);
      float var = Q * (1.f / 256.f) - mean * mean;
      mr_s[t][0] = mean; mr_s[t][1] = rsqrtf(var + 1e-5f);
    }
    __syncthreads();
#pragma unroll
    for (int rt = 0; rt < 4; ++rt)
#pragma unroll
      for (int r = 0; r < 4; ++r) {
        int row = rt * 16 + g * 4 + r;
        float mean = mr_s[row][0], rstd = mr_s[row][1];
#pragma unroll
        for (int ct = 0; ct < 2; ++ct)
          h[rt][ct][r] = (h[rt][ct][r] - mean) * rstd * c_lng[l][ncol[ct]] + c_lnb[l][ncol[ct]];
      }
    if (l == 0) S_REDUCE(c_ub[1], scal_s[3]);
  }

  // ---- stage 3: out = LN(h@Wout + bout) ----
#pragma unroll
  for (int rt = 0; rt < 4; ++rt)
#pragma unroll
    for (int ct = 0; ct < 2; ++ct)
#pragma unroll
      for (int r = 0; r < 4; ++r) {
        int row = rt * 16 + g * 4 + r;
        *(unsigned short*)(smc + alds_byte(ncol[ct], row)) = f2bf(h[rt][ct][r]);
      }
  __syncthreads();
  {
    f32x4 acc[4][2];
#pragma unroll
    for (int a = 0; a < 4; ++a)
#pragma unroll
      for (int c = 0; c < 2; ++c) { f32x4 z = {0.f, 0.f, 0.f, 0.f}; acc[a][c] = z; }
    kloop(smc, Uws + 65536, wid, lane, li, g, acc);
#pragma unroll
    for (int rt = 0; rt < 4; ++rt)
#pragma unroll
      for (int ct = 0; ct < 2; ++ct)
#pragma unroll
        for (int r = 0; r < 4; ++r) h[rt][ct][r] = acc[rt][ct][r] + c_bout[ncol[ct]];
    {  // LN stats via DPP
      float sA[16], sQ[16];
#pragma unroll
      for (int rt = 0; rt < 4; ++rt)
#pragma unroll
        for (int r = 0; r < 4; ++r) {
          float a0 = h[rt][0][r], a1 = h[rt][1][r];
          sA[rt * 4 + r] = a0 + a1;
          sQ[rt * 4 + r] = a0 * a0 + a1 * a1;
        }
#pragma unroll
      for (int i = 0; i < 16; ++i) { sA[i] = sum16(sA[i]); sQ[i] = sum16(sQ[i]); }
      if (li == 0) {
#pragma unroll
        for (int rt = 0; rt < 4; ++rt)
#pragma unroll
          for (int r = 0; r < 4; ++r) {
            int row = rt * 16 + g * 4 + r;
            red[wid][row][0] = sA[rt * 4 + r]; red[wid][row][1] = sQ[rt * 4 + r];
          }
      }
    }
    __syncthreads();
    if (t < 64) {
      float S = 0.f, Q = 0.f;
#pragma unroll
      for (int w = 0; w < 8; ++w) { S += red[w][t][0]; Q += red[w][t][1]; }
      float mean = S * (1.f / 256.f);
      float var = Q * (1.f / 256.f) - mean * mean;
      mr_s[t][0] = mean; mr_s[t][1] = rsqrtf(var + 1e-5f);
    }
    __syncthreads();
#pragma unroll
    for (int rt = 0; rt < 4; ++rt)
#pragma unroll
      for (int r = 0; r < 4; ++r) {
        int row = rt * 16 + g * 4 + r;
        float mean = mr_s[row][0], rstd = mr_s[row][1];
#pragma unroll
        for (int ct = 0; ct < 2; ++ct)
          out[(rowbase + row) * 256 + ncol[ct]] =
              (h[rt][ct][r] - mean) * rstd * c_lngf[ncol[ct]] + c_lnbf[ncol[ct]];
      }
  }
}

extern "C" void kernel_launch(void* const* d_in, const int* in_sizes, int n_in,
                              void* d_out, int out_size, void* d_ws, size_t ws_size,
                              hipStream_t stream) {
  const float* x    = (const float*)d_in[0];
  const int*   adj  = (const int*)d_in[1];
  const float* gdv  = (const float*)d_in[2];
  const float* Win  = (const float*)d_in[3];
  const float* bin  = (const float*)d_in[4];
  const float* Wout = (const float*)d_in[5];
  const float* bout = (const float*)d_in[6];
  const float* g1W  = (const float*)d_in[7];
  const float* g1b  = (const float*)d_in[8];
  const float* g2W  = (const float*)d_in[9];
  const float* g2b  = (const float*)d_in[10];
  const float* grW  = (const float*)d_in[11];
  const float* grb  = (const float*)d_in[12];
  const float* lngf = (const float*)d_in[13];
  const float* lnbf = (const float*)d_in[14];
  const float* Wf   = (const float*)d_in[15];
  const float* bfv  = (const float*)d_in[16];
  const float* Wt   = (const float*)d_in[17];
  const float* bt   = (const float*)d_in[18];
  const float* waf  = (const float*)d_in[19];
  const float* baf  = (const float*)d_in[20];
  const float* wat  = (const float*)d_in[21];
  const float* bat  = (const float*)d_in[22];
  const float* Wo   = (const float*)d_in[23];
  const float* bo   = (const float*)d_in[24];
  const float* lng  = (const float*)d_in[25];
  const float* lnb  = (const float*)d_in[26];
  float* out = (float*)d_out;

  float* W = (float*)d_ws;
  float* Tp = W;                                 // 2*256*256
  float* pb = W + 131072;                        // 512
  float* qb = W + 131584;
  float* rp = W + 132096;
  float* ub = W + 132608;
  float* cb = W + 133120;                        // 2 (+pad)
  unsigned short* Uws = (unsigned short*)(W + 133184);  // Win|Wout|M0|M1 swz bf16 (512KB)

  ta_kernel<<<512, 256, 0, stream>>>(gdv, g1W, g1b, g2W, g2b, grW, grb, Wt, bt, wat, Tp, pb, qb);
  tb_kernel<<<544, 256, 0, stream>>>(adj, Tp, pb, qb, bat, Wo, waf, baf, Wf, bfv, Win, Wout, rp, ub, cb, Uws);
  fused_kernel<<<512, 512, 0, stream>>>(x, rp, ub, cb, Uws, bin, bo, lng, lnb, bout, lngf, lnbf, out);
}

// Round 6
// 71.288 us; speedup vs baseline: 1.4793x; 1.0587x over previous
//
#include <hip/hip_runtime.h>
#include <hip/hip_bf16.h>

// GTAT integrated: B=8,N=4096,D=256,TD=64,GD=73,L=2 -> 32768 rows, row-parallel.
// TA (t,Tp,p,q) -> TB (beta,T_out,M=T_out@Wo swz, r',u,c, W swizzles)
//  -> fused (all 4 GEMM stages, h in registers, 64 rows/WG x 512 thr)
// R6: kill scratch spills for real — amdgpu_waves_per_eu(4,4) pins allocator at
//     128-VGPR budget (launch_bounds min alone let it squeeze to 64 + spill);
//     epilogue reductions restructured to 4-wide groups (peak live -24 regs).

typedef float f32x4 __attribute__((ext_vector_type(4)));
typedef short bf16x8 __attribute__((ext_vector_type(8)));

__device__ __forceinline__ unsigned short f2bf(float f) {
  unsigned int u = __builtin_bit_cast(unsigned int, f);
  u += 0x7FFFu + ((u >> 16) & 1u);   // round-to-nearest-even
  return (unsigned short)(u >> 16);
}
__device__ __forceinline__ float bf2f(unsigned short u) {
  return __builtin_bit_cast(float, (unsigned int)u << 16);
}
__device__ __forceinline__ float lrelu(float x) { return x > 0.f ? x : 0.01f * x; }

// ---- DPP 16-lane reduction (VALU only, no LDS pipe) ----
template <int CTRL>
__device__ __forceinline__ float dpp_ror_add(float v) {
  int s = __builtin_amdgcn_update_dpp(0, __builtin_bit_cast(int, v), CTRL, 0xf, 0xf, true);
  return v + __builtin_bit_cast(float, s);
}
__device__ __forceinline__ float sum16(float v) {   // all 16 lanes of each row get the sum
  v = dpp_ror_add<0x128>(v);  // row_ror:8
  v = dpp_ror_add<0x124>(v);  // row_ror:4
  v = dpp_ror_add<0x122>(v);  // row_ror:2
  v = dpp_ror_add<0x121>(v);  // row_ror:1
  return v;
}

// ---- block reduce helpers (256 threads, all must call) ----
__device__ __forceinline__ float block_sum(float v, float* s4, int t) {
  v = sum16(v);
  v += __shfl_xor(v, 16, 64);
  v += __shfl_xor(v, 32, 64);
  __syncthreads();
  if ((t & 63) == 0) s4[t >> 6] = v;
  __syncthreads();
  return s4[0] + s4[1] + s4[2] + s4[3];
}
__device__ __forceinline__ float block_max(float v, float* s4, int t) {
#pragma unroll
  for (int m = 1; m < 64; m <<= 1) v = fmaxf(v, __shfl_xor(v, m, 64));
  __syncthreads();
  if ((t & 63) == 0) s4[t >> 6] = v;
  __syncthreads();
  return fmaxf(fmaxf(s4[0], s4[1]), fmaxf(s4[2], s4[3]));
}

// B-operand swizzled layout: elem(k,n) -> ((((k>>5)*16 + (n>>4))*4 + ((k>>3)&3))*16 + (n&15))*8 + (k&7)
__device__ __forceinline__ int swz_off(int k, int n) {
  return ((((k >> 5) * 16 + (n >> 4)) * 4 + ((k >> 3) & 3)) * 16 + (n & 15)) * 8 + (k & 7);
}
// A-frag LDS byte offset for (k=n, row m in [0,64)), XOR-swizzled
__device__ __forceinline__ int alds_byte(int n, int m) {
  int grp = n >> 3;
  int base = (grp * 64 + m) * 16 + (n & 7) * 2;
  return base ^ ((grp & 7) << 4);
}

// ============ TA: t rows -> Tp rows + p,q  (grid 512 = L*256, 256 thr) ============
__global__ void ta_kernel(const float* __restrict__ gdv,
                          const float* __restrict__ g1W, const float* __restrict__ g1b,
                          const float* __restrict__ g2W, const float* __restrict__ g2b,
                          const float* __restrict__ grW, const float* __restrict__ grb,
                          const float* __restrict__ Wt, const float* __restrict__ bt,
                          const float* __restrict__ wat,
                          float* __restrict__ Tp, float* __restrict__ pb, float* __restrict__ qb) {
  int l = blockIdx.x >> 8, i = blockIdx.x & 255, t = threadIdx.x;
  __shared__ float gs[73], as_[64], ts[64], s4[4];
  float gv = (t < 73) ? gdv[i * 73 + t] : 0.f;
  float gsum = block_sum(gv, s4, t);
  if (t < 73) gs[t] = gv / (gsum + 1e-6f);
  __syncthreads();
  if (t < 64) {
    float a = g1b[t], gr = grb[t];
    for (int k = 0; k < 73; ++k) { float gk = gs[k]; a = fmaf(gk, g1W[k * 64 + t], a); gr = fmaf(gk, grW[k * 64 + t], gr); }
    as_[t] = fmaxf(a, 0.f);
    ts[t] = gr + g2b[t];
  }
  __syncthreads();
  float tv = 0.f;
  if (t < 64) {
    tv = ts[t];
    for (int k = 0; k < 64; ++k) tv = fmaf(as_[k], g2W[k * 64 + t], tv);
  }
  __syncthreads();
  if (t < 64) ts[t] = tv;
  __syncthreads();
  float tp = bt[l * 256 + t];
  for (int k = 0; k < 64; ++k) tp = fmaf(ts[k], Wt[(l * 64 + k) * 256 + t], tp);
  Tp[(l * 256 + i) * 256 + t] = tp;
  float pp = block_sum(tp * wat[l * 512 + t], s4, t);
  float qq = block_sum(tp * wat[l * 512 + 256 + t], s4, t);
  if (t == 0) { pb[l * 256 + i] = pp; qb[l * 256 + i] = qq; }
}

// ====== TB: beta,T_out row -> M row (swz bf16), r', u, c ; + W_in/W_out swizzles ======
__global__ void tb_kernel(const int* __restrict__ adj, const float* __restrict__ Tp,
                          const float* __restrict__ pb, const float* __restrict__ qb,
                          const float* __restrict__ batopo, const float* __restrict__ Wo,
                          const float* __restrict__ wafeat, const float* __restrict__ bafeat,
                          const float* __restrict__ Wf, const float* __restrict__ bfv,
                          const float* __restrict__ Win, const float* __restrict__ Wout,
                          float* __restrict__ rp, float* __restrict__ ub, float* __restrict__ cb,
                          unsigned short* __restrict__ Uws) {
  int b = blockIdx.x, t = threadIdx.x;
  if (b >= 512) {                               // weight swizzle blocks
    int bb = b - 512;
    const float* src = (bb < 16) ? Win : Wout;
    unsigned short* dst = Uws + ((bb < 16) ? 0 : 65536);
    int r0 = (bb & 15) * 16;
    for (int kk = 0; kk < 16; ++kk) {
      int k = r0 + kk;
      dst[swz_off(k, t)] = f2bf(src[k * 256 + t]);
    }
    return;
  }
  int l = b >> 8, i = b & 255;
  __shared__ float beta[256], tout[256], s4[4];
  float e = pb[l * 256 + i] + qb[l * 256 + t] + batopo[l];
  e = lrelu(e);
  if (adj[i * 256 + t] == 0) e = -1e9f;
  float mx = block_max(e, s4, t);
  float w = __expf(e - mx);
  float Z = block_sum(w, s4, t);
  beta[t] = w / Z;
  __syncthreads();
  float acc = 0.f;
  for (int j = 0; j < 256; ++j) acc = fmaf(beta[j], Tp[(l * 256 + j) * 256 + t], acc);
  tout[t] = acc;
  __syncthreads();
  const float* WoL = Wo + l * 65536;
  float macc = 0.f;
  for (int h2 = 0; h2 < 256; ++h2) macc = fmaf(tout[h2], WoL[h2 * 256 + t], macc);
  Uws[131072 + l * 65536 + swz_off(i, t)] = f2bf(macc);   // M_l row i
  const float* wf = wafeat + l * 512;
  float rsum = block_sum(tout[t] * wf[256 + t], s4, t);
  if (t == 0) rp[l * 256 + i] = rsum + bafeat[l];
  float usum = block_sum(Wf[(l * 256 + i) * 256 + t] * wf[t], s4, t);
  if (t == 0) ub[l * 256 + i] = usum;
  if (i == 0) {
    float csum = block_sum(bfv[l * 256 + t] * wf[t], s4, t);
    if (t == 0) cb[l] = csum;
  }
}

// ============ fused kernel: 4 GEMM stages, 512 WGs x 512 thr, 64 rows/WG ============
// wave tile = 64 rows x 32 cols (4x2 frags of 16x16x32). h in regs (32 f32/thread).
#define MFMA(A, B, C) __builtin_amdgcn_mfma_f32_16x16x32_bf16(A, B, C, 0, 0, 0)

__device__ __forceinline__ void kloop(const char* smc, const unsigned short* Bws,
                                      int wid, int lane, int li, int g, f32x4 acc[4][2]) {
  const bf16x8* Bw = (const bf16x8*)Bws + wid * 2 * 64 + lane;
  bf16x8 b0 = Bw[0], b1 = Bw[64];
#pragma unroll
  for (int kb = 0; kb < 8; ++kb) {
    bf16x8 nb0, nb1;
    if (kb < 7) {            // 1-deep B prefetch covers ~200cy L2 latency
      nb0 = Bw[(kb + 1) * 1024];
      nb1 = Bw[(kb + 1) * 1024 + 64];
    }
    int grp = kb * 4 + g;
    int ab = ((grp * 64 + li) * 16) ^ ((grp & 7) << 4);
    bf16x8 a0 = *(const bf16x8*)(smc + ab);
    bf16x8 a1 = *(const bf16x8*)(smc + ab + 256);
    bf16x8 a2 = *(const bf16x8*)(smc + ab + 512);
    bf16x8 a3 = *(const bf16x8*)(smc + ab + 768);
    acc[0][0] = MFMA(a0, b0, acc[0][0]);
    acc[1][0] = MFMA(a1, b0, acc[1][0]);
    acc[2][0] = MFMA(a2, b0, acc[2][0]);
    acc[3][0] = MFMA(a3, b0, acc[3][0]);
    acc[0][1] = MFMA(a0, b1, acc[0][1]);
    acc[1][1] = MFMA(a1, b1, acc[1][1]);
    acc[2][1] = MFMA(a2, b1, acc[2][1]);
    acc[3][1] = MFMA(a3, b1, acc[3][1]);
    if (kb < 7) { b0 = nb0; b1 = nb1; }
  }
}

// s = h . u + c per row; 4-wide groups to cap live temps
#define S_REDUCE(UBARR, CBV)                                                   \
  {                                                                            \
    float u0_ = UBARR[ncol[0]], u1_ = UBARR[ncol[1]];                          \
    _Pragma("unroll") for (int rt = 0; rt < 4; ++rt) {                         \
      float sp[4];                                                             \
      _Pragma("unroll") for (int r = 0; r < 4; ++r)                            \
        sp[r] = h[rt][0][r] * u0_ + h[rt][1][r] * u1_;                         \
      _Pragma("unroll") for (int r = 0; r < 4; ++r) sp[r] = sum16(sp[r]);      \
      if (li == 0) {                                                           \
        _Pragma("unroll") for (int r = 0; r < 4; ++r)                          \
          red[wid][rt * 16 + g * 4 + r][0] = sp[r];                            \
      }                                                                        \
    }                                                                          \
    __syncthreads();                                                           \
    if (t < 64) {                                                              \
      float S = 0.f;                                                           \
      _Pragma("unroll") for (int w = 0; w < 8; ++w) S += red[w][t][0];         \
      row_s[t] = S + (CBV);                                                    \
    }                                                                          \
    __syncthreads();                                                           \
  }

// LN stats (sum, sumsq) per row; 4-wide groups to cap live temps
#define LN_STATS()                                                             \
  {                                                                            \
    _Pragma("unroll") for (int rt = 0; rt < 4; ++rt) {                         \
      float sA[4], sQ[4];                                                      \
      _Pragma("unroll") for (int r = 0; r < 4; ++r) {                          \
        float a0 = h[rt][0][r], a1 = h[rt][1][r];                              \
        sA[r] = a0 + a1;                                                       \
        sQ[r] = a0 * a0 + a1 * a1;                                             \
      }                                                                        \
      _Pragma("unroll") for (int r = 0; r < 4; ++r) {                          \
        sA[r] = sum16(sA[r]); sQ[r] = sum16(sQ[r]);                            \
      }                                                                        \
      if (li == 0) {                                                           \
        _Pragma("unroll") for (int r = 0; r < 4; ++r) {                        \
          int row_ = rt * 16 + g * 4 + r;                                      \
          red[wid][row_][0] = sA[r]; red[wid][row_][1] = sQ[r];                \
        }                                                                      \
      }                                                                        \
    }                                                                          \
    __syncthreads();                                                           \
    if (t < 64) {                                                              \
      float S = 0.f, Q = 0.f;                                                  \
      _Pragma("unroll") for (int w = 0; w < 8; ++w) { S += red[w][t][0]; Q += red[w][t][1]; } \
      float mean_ = S * (1.f / 256.f);                                         \
      float var_ = Q * (1.f / 256.f) - mean_ * mean_;                          \
      mr_s[t][0] = mean_; mr_s[t][1] = rsqrtf(var_ + 1e-5f);                   \
    }                                                                          \
    __syncthreads();                                                           \
  }

__global__ void __launch_bounds__(512)
__attribute__((amdgpu_waves_per_eu(4, 4)))   // pin 4 waves/EU: VGPR budget 128, no spill
fused_kernel(
    const float* __restrict__ x,
    const float* __restrict__ rp, const float* __restrict__ ub, const float* __restrict__ cbp,
    const unsigned short* __restrict__ Uws,
    const float* __restrict__ bin, const float* __restrict__ bo,
    const float* __restrict__ lng, const float* __restrict__ lnb,
    const float* __restrict__ bout, const float* __restrict__ lngf, const float* __restrict__ lnbf,
    float* __restrict__ out) {
  // LDS 56.3KB keeps 2 blocks/CU (matches the 4-waves/EU pin with 8-wave blocks)
  __shared__ unsigned short alds[18432];
  __shared__ float c_bin[256], c_bout[256], c_lngf[256], c_lnbf[256];
  __shared__ float c_ub[2][256], c_bo[2][256], c_lng[2][256], c_lnb[2][256], c_rp[2][256];
  __shared__ float red[8][64][2];
  __shared__ float row_s[64], invz_s[64];
  __shared__ float mr_s[64][2];
  __shared__ float scal_s[4];                // Rm0, Rm1, cb0, cb1
  char* smc = (char*)alds;

  const int wg = blockIdx.x, t = threadIdx.x;
  const int wid = t >> 6, lane = t & 63, li = lane & 15, g = lane >> 4;
  const int rowbase = wg * 64;
  int ncol[2]; ncol[0] = wid * 32 + li; ncol[1] = wid * 32 + 16 + li;

  // constants -> LDS
  if (t < 256) {
    c_bin[t] = bin[t]; c_ub[0][t] = ub[t]; c_bo[0][t] = bo[t];
    c_lng[0][t] = lng[t]; c_lnb[0][t] = lnb[t]; c_rp[0][t] = rp[t];
  } else {
    int u = t - 256;
    c_bout[u] = bout[u]; c_lngf[u] = lngf[u]; c_lnbf[u] = lnbf[u];
    c_ub[1][u] = ub[256 + u]; c_bo[1][u] = bo[256 + u];
    c_lng[1][u] = lng[256 + u]; c_lnb[1][u] = lnb[256 + u]; c_rp[1][u] = rp[256 + u];
  }
  if (t == 0) { scal_s[2] = cbp[0]; scal_s[3] = cbp[1]; }

  // stage x -> alds (bf16, A-frag layout); coalesced float4 global reads
#pragma unroll
  for (int it = 0; it < 8; ++it) {
    int flat = it * 2048 + t * 4;
    int m = flat >> 8, col = flat & 255;
    const float4 xv = *(const float4*)(x + (rowbase + m) * 256 + col);
    ushort4 pk; pk.x = f2bf(xv.x); pk.y = f2bf(xv.y); pk.z = f2bf(xv.z); pk.w = f2bf(xv.w);
    *(ushort4*)(smc + alds_byte(col, m)) = pk;
  }
  __syncthreads();
  if (wid < 2) {   // Rm_l = max_f r'_l (once, 2 waves; shfl ok here)
    float m2 = fmaxf(fmaxf(c_rp[wid][lane], c_rp[wid][lane + 64]),
                     fmaxf(c_rp[wid][lane + 128], c_rp[wid][lane + 192]));
#pragma unroll
    for (int mm = 1; mm < 64; mm <<= 1) m2 = fmaxf(m2, __shfl_xor(m2, mm, 64));
    if (lane == 0) scal_s[wid] = m2;
  }

  float h[4][2][4];

  // ---- stage 0: h0 = x@Win + bin ; s0 ----
  {
    f32x4 acc[4][2];
#pragma unroll
    for (int a = 0; a < 4; ++a)
#pragma unroll
      for (int c = 0; c < 2; ++c) { f32x4 z = {0.f, 0.f, 0.f, 0.f}; acc[a][c] = z; }
    kloop(smc, Uws, wid, lane, li, g, acc);
#pragma unroll
    for (int rt = 0; rt < 4; ++rt)
#pragma unroll
      for (int ct = 0; ct < 2; ++ct)
#pragma unroll
        for (int r = 0; r < 4; ++r) h[rt][ct][r] = acc[rt][ct][r] + c_bin[ncol[ct]];
    S_REDUCE(c_ub[0], scal_s[2]);
  }

  // ---- layers ----
#pragma unroll 1
  for (int l = 0; l < 2; ++l) {
    // alpha (un-normalized bf16) -> alds via b128 writes; Z partials
    {
      int row = t & 63;                     // == lane
      float sm = row_s[row];
      float mx = lrelu(sm + scal_s[l]);     // exact max: lrelu monotone
      float z = 0.f;
#pragma unroll
      for (int it = 0; it < 4; ++it) {
        int grp = it * 8 + wid;
        float w0 = __expf(lrelu(sm + c_rp[l][grp * 8 + 0]) - mx);
        float w1 = __expf(lrelu(sm + c_rp[l][grp * 8 + 1]) - mx);
        float w2 = __expf(lrelu(sm + c_rp[l][grp * 8 + 2]) - mx);
        float w3 = __expf(lrelu(sm + c_rp[l][grp * 8 + 3]) - mx);
        float w4 = __expf(lrelu(sm + c_rp[l][grp * 8 + 4]) - mx);
        float w5 = __expf(lrelu(sm + c_rp[l][grp * 8 + 5]) - mx);
        float w6 = __expf(lrelu(sm + c_rp[l][grp * 8 + 6]) - mx);
        float w7 = __expf(lrelu(sm + c_rp[l][grp * 8 + 7]) - mx);
        unsigned short u0 = f2bf(w0), u1 = f2bf(w1), u2 = f2bf(w2), u3 = f2bf(w3);
        unsigned short u4 = f2bf(w4), u5 = f2bf(w5), u6 = f2bf(w6), u7 = f2bf(w7);
        z += bf2f(u0) + bf2f(u1) + bf2f(u2) + bf2f(u3) +
             bf2f(u4) + bf2f(u5) + bf2f(u6) + bf2f(u7);
        uint4 pk;
        pk.x = (unsigned int)u0 | ((unsigned int)u1 << 16);
        pk.y = (unsigned int)u2 | ((unsigned int)u3 << 16);
        pk.z = (unsigned int)u4 | ((unsigned int)u5 << 16);
        pk.w = (unsigned int)u6 | ((unsigned int)u7 << 16);
        int byte = ((grp * 64 + row) * 16) ^ ((grp & 7) << 4);
        *(uint4*)(smc + byte) = pk;
      }
      red[wid][row][0] = z;
    }
    __syncthreads();
    if (t < 64) {
      float Z = 0.f;
#pragma unroll
      for (int w = 0; w < 8; ++w) Z += red[w][t][0];
      invz_s[t] = 1.f / Z;
    }
    __syncthreads();

    f32x4 acc[4][2];
#pragma unroll
    for (int a = 0; a < 4; ++a)
#pragma unroll
      for (int c = 0; c < 2; ++c) { f32x4 z = {0.f, 0.f, 0.f, 0.f}; acc[a][c] = z; }
    kloop(smc, Uws + 131072 + l * 65536, wid, lane, li, g, acc);

    // h = LN(acc/Z + bo + h)
#pragma unroll
    for (int rt = 0; rt < 4; ++rt)
#pragma unroll
      for (int r = 0; r < 4; ++r) {
        int row = rt * 16 + g * 4 + r;
        float iz = invz_s[row];
#pragma unroll
        for (int ct = 0; ct < 2; ++ct)
          h[rt][ct][r] = fmaf(acc[rt][ct][r], iz, c_bo[l][ncol[ct]] + h[rt][ct][r]);
      }
    LN_STATS();
#pragma unroll
    for (int rt = 0; rt < 4; ++rt)
#pragma unroll
      for (int r = 0; r < 4; ++r) {
        int row = rt * 16 + g * 4 + r;
        float mean = mr_s[row][0], rstd = mr_s[row][1];
#pragma unroll
        for (int ct = 0; ct < 2; ++ct)
          h[rt][ct][r] = (h[rt][ct][r] - mean) * rstd * c_lng[l][ncol[ct]] + c_lnb[l][ncol[ct]];
      }
    if (l == 0) S_REDUCE(c_ub[1], scal_s[3]);
  }

  // ---- stage 3: out = LN(h@Wout + bout) ----
#pragma unroll
  for (int rt = 0; rt < 4; ++rt)
#pragma unroll
    for (int ct = 0; ct < 2; ++ct)
#pragma unroll
      for (int r = 0; r < 4; ++r) {
        int row = rt * 16 + g * 4 + r;
        *(unsigned short*)(smc + alds_byte(ncol[ct], row)) = f2bf(h[rt][ct][r]);
      }
  __syncthreads();
  {
    f32x4 acc[4][2];
#pragma unroll
    for (int a = 0; a < 4; ++a)
#pragma unroll
      for (int c = 0; c < 2; ++c) { f32x4 z = {0.f, 0.f, 0.f, 0.f}; acc[a][c] = z; }
    kloop(smc, Uws + 65536, wid, lane, li, g, acc);
#pragma unroll
    for (int rt = 0; rt < 4; ++rt)
#pragma unroll
      for (int ct = 0; ct < 2; ++ct)
#pragma unroll
        for (int r = 0; r < 4; ++r) h[rt][ct][r] = acc[rt][ct][r] + c_bout[ncol[ct]];
    LN_STATS();
#pragma unroll
    for (int rt = 0; rt < 4; ++rt)
#pragma unroll
      for (int r = 0; r < 4; ++r) {
        int row = rt * 16 + g * 4 + r;
        float mean = mr_s[row][0], rstd = mr_s[row][1];
#pragma unroll
        for (int ct = 0; ct < 2; ++ct)
          out[(rowbase + row) * 256 + ncol[ct]] =
              (h[rt][ct][r] - mean) * rstd * c_lngf[ncol[ct]] + c_lnbf[ncol[ct]];
      }
  }
}

extern "C" void kernel_launch(void* const* d_in, const int* in_sizes, int n_in,
                              void* d_out, int out_size, void* d_ws, size_t ws_size,
                              hipStream_t stream) {
  const float* x    = (const float*)d_in[0];
  const int*   adj  = (const int*)d_in[1];
  const float* gdv  = (const float*)d_in[2];
  const float* Win  = (const float*)d_in[3];
  const float* bin  = (const float*)d_in[4];
  const float* Wout = (const float*)d_in[5];
  const float* bout = (const float*)d_in[6];
  const float* g1W  = (const float*)d_in[7];
  const float* g1b  = (const float*)d_in[8];
  const float* g2W  = (const float*)d_in[9];
  const float* g2b  = (const float*)d_in[10];
  const float* grW  = (const float*)d_in[11];
  const float* grb  = (const float*)d_in[12];
  const float* lngf = (const float*)d_in[13];
  const float* lnbf = (const float*)d_in[14];
  const float* Wf   = (const float*)d_in[15];
  const float* bfv  = (const float*)d_in[16];
  const float* Wt   = (const float*)d_in[17];
  const float* bt   = (const float*)d_in[18];
  const float* waf  = (const float*)d_in[19];
  const float* baf  = (const float*)d_in[20];
  const float* wat  = (const float*)d_in[21];
  const float* bat  = (const float*)d_in[22];
  const float* Wo   = (const float*)d_in[23];
  const float* bo   = (const float*)d_in[24];
  const float* lng  = (const float*)d_in[25];
  const float* lnb  = (const float*)d_in[26];
  float* out = (float*)d_out;

  float* W = (float*)d_ws;
  float* Tp = W;                                 // 2*256*256
  float* pb = W + 131072;                        // 512
  float* qb = W + 131584;
  float* rp = W + 132096;
  float* ub = W + 132608;
  float* cb = W + 133120;                        // 2 (+pad)
  unsigned short* Uws = (unsigned short*)(W + 133184);  // Win|Wout|M0|M1 swz bf16 (512KB)

  ta_kernel<<<512, 256, 0, stream>>>(gdv, g1W, g1b, g2W, g2b, grW, grb, Wt, bt, wat, Tp, pb, qb);
  tb_kernel<<<544, 256, 0, stream>>>(adj, Tp, pb, qb, bat, Wo, waf, baf, Wf, bfv, Win, Wout, rp, ub, cb, Uws);
  fused_kernel<<<512, 512, 0, stream>>>(x, rp, ub, cb, Uws, bin, bo, lng, lnb, bout, lngf, lnbf, out);
}